// Round 1
// baseline (1709.787 us; speedup 1.0000x reference)
//
#include <hip/hip_runtime.h>

// GATv2 stack on MI355X. fp32 throughout (no fp32 MFMA on CDNA4 -> vector ALU).
// Strategy: build CSR-by-dst once, then per-dst-wave attention kernels with
// zero atomics in the hot loops; logits round-trip through a global scratch.

static __device__ __forceinline__ float lrelu(float x, float s) {
    return x > 0.f ? x : s * x;
}

// ---------------- graph build ----------------

__global__ void k_degree(const int* __restrict__ dst, const float* __restrict__ ea,
                         int* __restrict__ cnt, float* __restrict__ esum, int E) {
    int e = blockIdx.x * blockDim.x + threadIdx.x;
    if (e >= E) return;
    int d = dst[e];
    atomicAdd(&cnt[d], 1);
    atomicAdd(&esum[2 * d], ea[2 * e]);
    atomicAdd(&esum[2 * d + 1], ea[2 * e + 1]);
}

// exclusive scan of (cnt[i]+1) -> row_ptr, single block of 1024 threads
__launch_bounds__(1024)
__global__ void k_rowptr(const int* __restrict__ cnt, int* __restrict__ row_ptr, int n) {
    __shared__ int tot[1024];
    int t = threadIdx.x;
    int chunk = (n + 1023) >> 10;
    int b = min(t * chunk, n), e = min(b + chunk, n);
    int s = 0;
    for (int i = b; i < e; ++i) s += cnt[i] + 1;
    tot[t] = s;
    __syncthreads();
    for (int off = 1; off < 1024; off <<= 1) {
        int v = (t >= off) ? tot[t - off] : 0;
        __syncthreads();
        tot[t] += v;
        __syncthreads();
    }
    int run = (t > 0) ? tot[t - 1] : 0;
    for (int i = b; i < e; ++i) { row_ptr[i] = run; run += cnt[i] + 1; }
    if (t == 1023) row_ptr[n] = run;
}

__global__ void k_scatter(const int* __restrict__ src, const int* __restrict__ dst,
                          const float* __restrict__ ea,
                          const int* __restrict__ row_ptr, int* __restrict__ fill,
                          int* __restrict__ csr_src, float* __restrict__ csr_ea, int E) {
    int e = blockIdx.x * blockDim.x + threadIdx.x;
    if (e >= E) return;
    int d = dst[e];
    int pos = row_ptr[d] + atomicAdd(&fill[d], 1);
    csr_src[pos] = src[e];
    csr_ea[2 * (size_t)pos] = ea[2 * (size_t)e];
    csr_ea[2 * (size_t)pos + 1] = ea[2 * (size_t)e + 1];
}

// self loop goes in the last slot of each segment; attr = mean of incoming
__global__ void k_selfloop(const int* __restrict__ row_ptr, const int* __restrict__ cnt,
                           const float* __restrict__ esum,
                           int* __restrict__ csr_src, float* __restrict__ csr_ea, int n) {
    int i = blockIdx.x * blockDim.x + threadIdx.x;
    if (i >= n) return;
    int p = row_ptr[i + 1] - 1;
    csr_src[p] = i;
    float c = fmaxf((float)cnt[i], 1.f);
    csr_ea[2 * (size_t)p] = esum[2 * i] / c;
    csr_ea[2 * (size_t)p + 1] = esum[2 * i + 1] / c;
}

// ---------------- projections ----------------

// layer-0: x[N,2] @ W[2,64] + b  (both l and r)
__global__ void k_proj0(const float* __restrict__ x,
                        const float* __restrict__ Wl, const float* __restrict__ bl,
                        const float* __restrict__ Wr, const float* __restrict__ br,
                        float* __restrict__ xl, float* __restrict__ xr, int n) {
    int idx = blockIdx.x * blockDim.x + threadIdx.x;
    if (idx >= n * 64) return;
    int i = idx >> 6, c = idx & 63;
    float x0 = x[2 * i], x1 = x[2 * i + 1];
    xl[idx] = x0 * Wl[c] + x1 * Wl[64 + c] + bl[c];
    xr[idx] = x0 * Wr[c] + x1 * Wr[64 + c] + br[c];
}

// h[N,64] @ W[64,64] + b. blockIdx.y selects (Wl->xl) or (Wr->xr).
// Thread computes 4 rows x 16 cols; W in LDS (2-way bank alias only), h via float4.
__launch_bounds__(256)
__global__ void k_proj64_dual(const float* __restrict__ h,
                              const float* __restrict__ Wl, const float* __restrict__ bl,
                              const float* __restrict__ Wr, const float* __restrict__ br,
                              float* __restrict__ xl, float* __restrict__ xr, int n) {
    __shared__ float ws[4096];
    const float* W = blockIdx.y ? Wr : Wl;
    const float* bias = blockIdx.y ? br : bl;
    float* out = blockIdx.y ? xr : xl;
    int t = threadIdx.x;
    for (int i = t; i < 4096; i += 256) ws[i] = W[i];
    __syncthreads();
    int rg = t >> 2, cg = (t & 3) << 4;
    int r0 = blockIdx.x * 256 + rg * 4;
    float acc[4][16];
#pragma unroll
    for (int r = 0; r < 4; ++r)
#pragma unroll
        for (int j = 0; j < 16; ++j) acc[r][j] = 0.f;
    for (int k0 = 0; k0 < 64; k0 += 4) {
        float hk[4][4];
#pragma unroll
        for (int r = 0; r < 4; ++r) {
            int gr = r0 + r;
            float4 v = (gr < n) ? *(const float4*)(h + (size_t)gr * 64 + k0)
                                : make_float4(0.f, 0.f, 0.f, 0.f);
            hk[r][0] = v.x; hk[r][1] = v.y; hk[r][2] = v.z; hk[r][3] = v.w;
        }
#pragma unroll
        for (int kk = 0; kk < 4; ++kk) {
            const float* wrow = ws + (k0 + kk) * 64 + cg;
#pragma unroll
            for (int r = 0; r < 4; ++r)
#pragma unroll
                for (int j = 0; j < 16; ++j) acc[r][j] += hk[r][kk] * wrow[j];
        }
    }
#pragma unroll
    for (int r = 0; r < 4; ++r) {
        int gr = r0 + r;
        if (gr < n) {
            float* o = out + (size_t)gr * 64 + cg;
#pragma unroll
            for (int j = 0; j < 16; ++j) o[j] = acc[r][j] + bias[cg + j];
        }
    }
}

// final projections fused: packed[i][0:16)=f_xl, [16:32)=s_xl, [32:48)=f_xr, [48:64)=s_xr
__launch_bounds__(256)
__global__ void k_proj_final(const float* __restrict__ h,
                             const float* __restrict__ fWl, const float* __restrict__ fbl,
                             const float* __restrict__ fWr, const float* __restrict__ fbr,
                             const float* __restrict__ sWl, const float* __restrict__ sbl,
                             const float* __restrict__ sWr, const float* __restrict__ sbr,
                             float* __restrict__ packed, int n) {
    __shared__ float ws[4096];
    __shared__ float bs[64];
    int t = threadIdx.x;
    for (int i = t; i < 1024; i += 256) {
        int k = i >> 4, j = i & 15;
        ws[k * 64 + j] = fWl[i];
        ws[k * 64 + 16 + j] = sWl[i];
        ws[k * 64 + 32 + j] = fWr[i];
        ws[k * 64 + 48 + j] = sWr[i];
    }
    if (t < 16) { bs[t] = fbl[t]; bs[16 + t] = sbl[t]; bs[32 + t] = fbr[t]; bs[48 + t] = sbr[t]; }
    __syncthreads();
    int rg = t >> 2, cg = (t & 3) << 4;
    int r0 = blockIdx.x * 256 + rg * 4;
    float acc[4][16];
#pragma unroll
    for (int r = 0; r < 4; ++r)
#pragma unroll
        for (int j = 0; j < 16; ++j) acc[r][j] = 0.f;
    for (int k0 = 0; k0 < 64; k0 += 4) {
        float hk[4][4];
#pragma unroll
        for (int r = 0; r < 4; ++r) {
            int gr = r0 + r;
            float4 v = (gr < n) ? *(const float4*)(h + (size_t)gr * 64 + k0)
                                : make_float4(0.f, 0.f, 0.f, 0.f);
            hk[r][0] = v.x; hk[r][1] = v.y; hk[r][2] = v.z; hk[r][3] = v.w;
        }
#pragma unroll
        for (int kk = 0; kk < 4; ++kk) {
            const float* wrow = ws + (k0 + kk) * 64 + cg;
#pragma unroll
            for (int r = 0; r < 4; ++r)
#pragma unroll
                for (int j = 0; j < 16; ++j) acc[r][j] += hk[r][kk] * wrow[j];
        }
    }
#pragma unroll
    for (int r = 0; r < 4; ++r) {
        int gr = r0 + r;
        if (gr < n) {
            float* o = packed + (size_t)gr * 64 + cg;
#pragma unroll
            for (int j = 0; j < 16; ++j) o[j] = acc[r][j] + bs[cg + j];
        }
    }
}

// ---------------- GATv2 attention, 64-feature layers ----------------
// one wave per dst node; lane = head*4 + channel
__launch_bounds__(256)
__global__ void k_gat(const float* __restrict__ xl, const float* __restrict__ xr,
                      const int* __restrict__ row_ptr, const int* __restrict__ csr_src,
                      const float* __restrict__ csr_ea,
                      const float* __restrict__ We,   // [2,64]
                      const float* __restrict__ att,  // [16,4] flat
                      const float* __restrict__ bias, // [64]
                      float* __restrict__ out, float* __restrict__ lscr,
                      int n, int relu) {
    int wave = (blockIdx.x * blockDim.x + threadIdx.x) >> 6;
    int lane = threadIdx.x & 63;
    if (wave >= n) return;
    const int d = wave;
    const int p0 = row_ptr[d], p1 = row_ptr[d + 1];
    const int hh = lane >> 2;
    const float we0 = We[lane], we1 = We[64 + lane];
    const float av = att[lane];
    const float xrv = xr[(size_t)d * 64 + lane];
    float mx = -3.0e38f;
    // pass 1: logits -> scratch, running per-head max
    for (int p = p0; p < p1; ++p) {
        int s = csr_src[p];
        float2 ea = *(const float2*)(csr_ea + 2 * (size_t)p);
        float m = xl[(size_t)s * 64 + lane] + xrv + ea.x * we0 + ea.y * we1;
        m = lrelu(m, 0.2f);
        float tv = m * av;
        tv += __shfl_xor(tv, 1);
        tv += __shfl_xor(tv, 2);   // quad-reduce: every lane of quad hh holds logit
        if ((lane & 3) == 0) lscr[(size_t)p * 16 + hh] = tv;
        mx = fmaxf(mx, tv);
    }
    // make our own scratch writes visible to our reads
    __asm__ volatile("s_waitcnt vmcnt(0)" ::: "memory");
    // pass 2: denominator. lane handles head (lane&15), edge offset (lane>>4)
    float mxh = __shfl(mx, (lane & 15) << 2);
    float den = 0.f;
    for (int p = p0 + (lane >> 4); p < p1; p += 4)
        den += __expf(lscr[(size_t)p * 16 + (lane & 15)] - mxh);
    den += __shfl_xor(den, 16);
    den += __shfl_xor(den, 32);
    float invd = 1.f / __shfl(den, hh);
    // pass 3: weighted aggregation
    float acc = 0.f;
    for (int p = p0; p < p1; ++p) {
        int s = csr_src[p];
        float a = __expf(lscr[(size_t)p * 16 + hh] - mx) * invd;
        acc += a * xl[(size_t)s * 64 + lane];
    }
    float o = acc + bias[lane];
    if (relu) o = lrelu(o, 0.01f);
    out[(size_t)d * 64 + lane] = o;
}

// ---------------- final two H=16,C=1 layers fused ----------------
// half-wave per dst: lanes 0-15 = f (-> fin), 16-31 = s (-> mus)
__launch_bounds__(256)
__global__ void k_gat_final(const float* __restrict__ packed,
                            const int* __restrict__ row_ptr, const int* __restrict__ csr_src,
                            const float* __restrict__ csr_ea,
                            const float* __restrict__ fWe, const float* __restrict__ sWe,
                            const float* __restrict__ fatt, const float* __restrict__ satt,
                            const float* __restrict__ fbias, const float* __restrict__ sbias,
                            float* __restrict__ fin, float* __restrict__ mus, int n) {
    int hw = (blockIdx.x * blockDim.x + threadIdx.x) >> 5;
    if (hw >= n) return;
    int l = threadIdx.x & 31;
    int hh = l & 15, sel = l >> 4;
    const int d = hw;
    const int p0 = row_ptr[d], p1 = row_ptr[d + 1];
    const float* We = sel ? sWe : fWe;
    float we0 = We[hh], we1 = We[16 + hh];
    float av = (sel ? satt : fatt)[hh];
    float xrv = packed[(size_t)d * 64 + 32 + sel * 16 + hh];
    int xli = sel * 16 + hh;
    float mx = -3.0e38f;
    for (int p = p0; p < p1; ++p) {
        int s = csr_src[p];
        float2 ea = *(const float2*)(csr_ea + 2 * (size_t)p);
        float m = lrelu(packed[(size_t)s * 64 + xli] + xrv + ea.x * we0 + ea.y * we1, 0.2f);
        mx = fmaxf(mx, m * av);
    }
    float den = 0.f;
    for (int p = p0; p < p1; ++p) {
        int s = csr_src[p];
        float2 ea = *(const float2*)(csr_ea + 2 * (size_t)p);
        float m = lrelu(packed[(size_t)s * 64 + xli] + xrv + ea.x * we0 + ea.y * we1, 0.2f);
        den += __expf(m * av - mx);
    }
    float invd = 1.f / den;
    float acc = 0.f;
    for (int p = p0; p < p1; ++p) {
        int s = csr_src[p];
        float2 ea = *(const float2*)(csr_ea + 2 * (size_t)p);
        float xlv = packed[(size_t)s * 64 + xli];
        float m = lrelu(xlv + xrv + ea.x * we0 + ea.y * we1, 0.2f);
        acc += __expf(m * av - mx) * invd * xlv;
    }
#pragma unroll
    for (int w = 1; w < 16; w <<= 1) acc += __shfl_xor(acc, w);
    if ((threadIdx.x & 15) == 0) {
        float o = acc * (1.f / 16.f) + (sel ? sbias[0] : fbias[0]);
        if (sel) mus[d] = o; else fin[d] = o;
    }
}

// ---------------- batchnorm ----------------

__global__ void k_bnstats(const float* __restrict__ h, double* __restrict__ stats, int n) {
    int c = threadIdx.x & 63;
    int s0 = blockIdx.x * (blockDim.x >> 6) + (threadIdx.x >> 6);
    int ns = gridDim.x * (blockDim.x >> 6);
    double s = 0.0, s2 = 0.0;
    for (int i = s0; i < n; i += ns) {
        float v = h[(size_t)i * 64 + c];
        s += v;
        s2 += (double)v * v;
    }
    atomicAdd(&stats[c], s);
    atomicAdd(&stats[64 + c], s2);
}

__global__ void k_bnapply(float* __restrict__ h, const double* __restrict__ stats,
                          const float* __restrict__ gamma, const float* __restrict__ beta, int n) {
    int idx = blockIdx.x * blockDim.x + threadIdx.x;
    if (idx >= n * 64) return;
    int c = idx & 63;
    double mu = stats[c] / n;
    double var = stats[64 + c] / n - mu * mu;
    float rs = (float)(1.0 / sqrt(var + 1e-5));
    float v = (h[idx] - (float)mu) * rs * gamma[c] + beta[c];
    h[idx] = lrelu(v, 0.01f);
}

// ---------------- graph-level mean over masked nodes ----------------

__global__ void k_sat_acc(const float* __restrict__ fin, const int* __restrict__ mask,
                          const int* __restrict__ batch,
                          float* __restrict__ sums, float* __restrict__ cnts, int n) {
    int i = blockIdx.x * blockDim.x + threadIdx.x;
    if (i >= n) return;
    if (mask[i] == 0) {
        int g = batch[i];
        atomicAdd(&sums[g], fin[i]);
        atomicAdd(&cnts[g], 1.f);
    }
}

__global__ void k_sat_fin(const float* __restrict__ sums, const float* __restrict__ cnts,
                          float* __restrict__ out, int g) {
    int i = threadIdx.x;
    if (i < g) out[i] = sums[i] / fmaxf(cnts[i], 1.f);
}

// ---------------- host ----------------

extern "C" void kernel_launch(void* const* d_in, const int* in_sizes, int n_in,
                              void* d_out, int out_size, void* d_ws, size_t ws_size,
                              hipStream_t stream) {
    const float* x = (const float*)d_in[0];
    const float* eat = (const float*)d_in[1];
    const int* ei = (const int*)d_in[2];
    const int* mask = (const int*)d_in[3];
    const int* batch = (const int*)d_in[4];
    const float* g0_Wl = (const float*)d_in[5];
    const float* g0_bl = (const float*)d_in[6];
    const float* g0_Wr = (const float*)d_in[7];
    const float* g0_br = (const float*)d_in[8];
    const float* g0_We = (const float*)d_in[9];
    const float* g0_att = (const float*)d_in[10];
    const float* g0_bias = (const float*)d_in[11];
    const float* bn_g = (const float*)d_in[12];
    const float* bn_b = (const float*)d_in[13];
    const float* m_Wl = (const float*)d_in[14];
    const float* m_bl = (const float*)d_in[15];
    const float* m_Wr = (const float*)d_in[16];
    const float* m_br = (const float*)d_in[17];
    const float* m_We = (const float*)d_in[18];
    const float* m_att = (const float*)d_in[19];
    const float* m_bias = (const float*)d_in[20];
    const float* f_Wl = (const float*)d_in[21];
    const float* f_bl = (const float*)d_in[22];
    const float* f_Wr = (const float*)d_in[23];
    const float* f_br = (const float*)d_in[24];
    const float* f_We = (const float*)d_in[25];
    const float* f_att = (const float*)d_in[26];
    const float* f_bias = (const float*)d_in[27];
    const float* s_Wl = (const float*)d_in[28];
    const float* s_bl = (const float*)d_in[29];
    const float* s_Wr = (const float*)d_in[30];
    const float* s_br = (const float*)d_in[31];
    const float* s_We = (const float*)d_in[32];
    const float* s_att = (const float*)d_in[33];
    const float* s_bias = (const float*)d_in[34];

    const int N = in_sizes[3];
    const int E = in_sizes[1] / 2;
    const int G = out_size - N;
    const int ITER = in_sizes[14] / 4096;
    const int ET = E + N;
    const int* srcp = ei;
    const int* dstp = ei + E;

    char* wsb = (char*)d_ws;
    size_t off = 0;
    auto alloc = [&](size_t b) { void* p = wsb + off; off = (off + b + 255) & ~(size_t)255; return p; };
    int* cnt = (int*)alloc((size_t)N * 4);
    float* esum = (float*)alloc((size_t)N * 8);
    int* fill = (int*)alloc((size_t)N * 4);
    double* stats = (double*)alloc(128 * 8);
    float* sums = (float*)alloc((size_t)G * 4);
    float* cnts = (float*)alloc((size_t)G * 4);
    size_t zero_bytes = off;
    int* row_ptr = (int*)alloc((size_t)(N + 1) * 4);
    int* csr_src = (int*)alloc((size_t)ET * 4);
    float* csr_ea = (float*)alloc((size_t)ET * 8);
    float* xl = (float*)alloc((size_t)N * 256);
    float* xr = (float*)alloc((size_t)N * 256);
    float* hbuf = (float*)alloc((size_t)N * 256);
    float* fin = (float*)alloc((size_t)N * 4);
    float* lscr = (float*)alloc((size_t)ET * 64);
    (void)ws_size; (void)n_in;

    float* outv = (float*)d_out;  // [0,N) = mus, [N,N+G) = sat

    hipMemsetAsync(d_ws, 0, zero_bytes, stream);
    const int tb = 256;
    k_degree<<<(E + tb - 1) / tb, tb, 0, stream>>>(dstp, eat, cnt, esum, E);
    k_rowptr<<<1, 1024, 0, stream>>>(cnt, row_ptr, N);
    k_scatter<<<(E + tb - 1) / tb, tb, 0, stream>>>(srcp, dstp, eat, row_ptr, fill, csr_src, csr_ea, E);
    k_selfloop<<<(N + tb - 1) / tb, tb, 0, stream>>>(row_ptr, cnt, esum, csr_src, csr_ea, N);

    k_proj0<<<(N * 64 + tb - 1) / tb, tb, 0, stream>>>(x, g0_Wl, g0_bl, g0_Wr, g0_br, xl, xr, N);
    k_gat<<<(N * 64 + tb - 1) / tb, tb, 0, stream>>>(xl, xr, row_ptr, csr_src, csr_ea,
                                                     g0_We, g0_att, g0_bias, hbuf, lscr, N, 0);
    k_bnstats<<<128, 256, 0, stream>>>(hbuf, stats, N);
    k_bnapply<<<(N * 64 + tb - 1) / tb, tb, 0, stream>>>(hbuf, stats, bn_g, bn_b, N);

    dim3 gp((N + 255) / 256, 2);
    for (int l = 0; l < ITER; ++l) {
        k_proj64_dual<<<gp, 256, 0, stream>>>(hbuf, m_Wl + (size_t)l * 4096, m_bl + l * 64,
                                              m_Wr + (size_t)l * 4096, m_br + l * 64, xl, xr, N);
        k_gat<<<(N * 64 + tb - 1) / tb, tb, 0, stream>>>(xl, xr, row_ptr, csr_src, csr_ea,
                                                         m_We + l * 128, m_att + l * 64,
                                                         m_bias + l * 64, hbuf, lscr, N, 1);
    }
    k_proj_final<<<(N + 255) / 256, 256, 0, stream>>>(hbuf, f_Wl, f_bl, f_Wr, f_br,
                                                      s_Wl, s_bl, s_Wr, s_br, xl, N);
    k_gat_final<<<(N * 32 + tb - 1) / tb, tb, 0, stream>>>(xl, row_ptr, csr_src, csr_ea,
                                                           f_We, s_We, f_att, s_att,
                                                           f_bias, s_bias, fin, outv, N);
    k_sat_acc<<<(N + tb - 1) / tb, tb, 0, stream>>>(fin, mask, batch, sums, cnts, N);
    k_sat_fin<<<1, 64, 0, stream>>>(sums, cnts, outv + N, G);
}

// Round 2
// 952.731 us; speedup vs baseline: 1.7946x; 1.7946x over previous
//
#include <hip/hip_runtime.h>

// GATv2 stack on MI355X. fp32 throughout (no fp32 MFMA on CDNA4 -> vector ALU).
// R1: online-softmax single-pass attention (no logit scratch, one gather/edge),
// unroll-2 edge loop for 2x memory-level parallelism.

static __device__ __forceinline__ float lrelu(float x, float s) {
    return x > 0.f ? x : s * x;
}

// ---------------- graph build ----------------

__global__ void k_degree(const int* __restrict__ dst, const float* __restrict__ ea,
                         int* __restrict__ cnt, float* __restrict__ esum, int E) {
    int e = blockIdx.x * blockDim.x + threadIdx.x;
    if (e >= E) return;
    int d = dst[e];
    atomicAdd(&cnt[d], 1);
    atomicAdd(&esum[2 * d], ea[2 * e]);
    atomicAdd(&esum[2 * d + 1], ea[2 * e + 1]);
}

__launch_bounds__(1024)
__global__ void k_rowptr(const int* __restrict__ cnt, int* __restrict__ row_ptr, int n) {
    __shared__ int tot[1024];
    int t = threadIdx.x;
    int chunk = (n + 1023) >> 10;
    int b = min(t * chunk, n), e = min(b + chunk, n);
    int s = 0;
    for (int i = b; i < e; ++i) s += cnt[i] + 1;
    tot[t] = s;
    __syncthreads();
    for (int off = 1; off < 1024; off <<= 1) {
        int v = (t >= off) ? tot[t - off] : 0;
        __syncthreads();
        tot[t] += v;
        __syncthreads();
    }
    int run = (t > 0) ? tot[t - 1] : 0;
    for (int i = b; i < e; ++i) { row_ptr[i] = run; run += cnt[i] + 1; }
    if (t == 1023) row_ptr[n] = run;
}

__global__ void k_scatter(const int* __restrict__ src, const int* __restrict__ dst,
                          const float* __restrict__ ea,
                          const int* __restrict__ row_ptr, int* __restrict__ fill,
                          int* __restrict__ csr_src, float* __restrict__ csr_ea, int E) {
    int e = blockIdx.x * blockDim.x + threadIdx.x;
    if (e >= E) return;
    int d = dst[e];
    int pos = row_ptr[d] + atomicAdd(&fill[d], 1);
    csr_src[pos] = src[e];
    csr_ea[2 * (size_t)pos] = ea[2 * (size_t)e];
    csr_ea[2 * (size_t)pos + 1] = ea[2 * (size_t)e + 1];
}

__global__ void k_selfloop(const int* __restrict__ row_ptr, const int* __restrict__ cnt,
                           const float* __restrict__ esum,
                           int* __restrict__ csr_src, float* __restrict__ csr_ea, int n) {
    int i = blockIdx.x * blockDim.x + threadIdx.x;
    if (i >= n) return;
    int p = row_ptr[i + 1] - 1;
    csr_src[p] = i;
    float c = fmaxf((float)cnt[i], 1.f);
    csr_ea[2 * (size_t)p] = esum[2 * i] / c;
    csr_ea[2 * (size_t)p + 1] = esum[2 * i + 1] / c;
}

// ---------------- projections ----------------

__global__ void k_proj0(const float* __restrict__ x,
                        const float* __restrict__ Wl, const float* __restrict__ bl,
                        const float* __restrict__ Wr, const float* __restrict__ br,
                        float* __restrict__ xl, float* __restrict__ xr, int n) {
    int idx = blockIdx.x * blockDim.x + threadIdx.x;
    if (idx >= n * 64) return;
    int i = idx >> 6, c = idx & 63;
    float x0 = x[2 * i], x1 = x[2 * i + 1];
    xl[idx] = x0 * Wl[c] + x1 * Wl[64 + c] + bl[c];
    xr[idx] = x0 * Wr[c] + x1 * Wr[64 + c] + br[c];
}

__launch_bounds__(256)
__global__ void k_proj64_dual(const float* __restrict__ h,
                              const float* __restrict__ Wl, const float* __restrict__ bl,
                              const float* __restrict__ Wr, const float* __restrict__ br,
                              float* __restrict__ xl, float* __restrict__ xr, int n) {
    __shared__ float ws[4096];
    const float* W = blockIdx.y ? Wr : Wl;
    const float* bias = blockIdx.y ? br : bl;
    float* out = blockIdx.y ? xr : xl;
    int t = threadIdx.x;
    for (int i = t; i < 4096; i += 256) ws[i] = W[i];
    __syncthreads();
    int rg = t >> 2, cg = (t & 3) << 4;
    int r0 = blockIdx.x * 256 + rg * 4;
    float acc[4][16];
#pragma unroll
    for (int r = 0; r < 4; ++r)
#pragma unroll
        for (int j = 0; j < 16; ++j) acc[r][j] = 0.f;
    for (int k0 = 0; k0 < 64; k0 += 4) {
        float hk[4][4];
#pragma unroll
        for (int r = 0; r < 4; ++r) {
            int gr = r0 + r;
            float4 v = (gr < n) ? *(const float4*)(h + (size_t)gr * 64 + k0)
                                : make_float4(0.f, 0.f, 0.f, 0.f);
            hk[r][0] = v.x; hk[r][1] = v.y; hk[r][2] = v.z; hk[r][3] = v.w;
        }
#pragma unroll
        for (int kk = 0; kk < 4; ++kk) {
            const float* wrow = ws + (k0 + kk) * 64 + cg;
#pragma unroll
            for (int r = 0; r < 4; ++r)
#pragma unroll
                for (int j = 0; j < 16; ++j) acc[r][j] += hk[r][kk] * wrow[j];
        }
    }
#pragma unroll
    for (int r = 0; r < 4; ++r) {
        int gr = r0 + r;
        if (gr < n) {
            float* o = out + (size_t)gr * 64 + cg;
#pragma unroll
            for (int j = 0; j < 16; ++j) o[j] = acc[r][j] + bias[cg + j];
        }
    }
}

// final projections fused: packed[i][0:16)=f_xl, [16:32)=s_xl, [32:48)=f_xr, [48:64)=s_xr
__launch_bounds__(256)
__global__ void k_proj_final(const float* __restrict__ h,
                             const float* __restrict__ fWl, const float* __restrict__ fbl,
                             const float* __restrict__ fWr, const float* __restrict__ fbr,
                             const float* __restrict__ sWl, const float* __restrict__ sbl,
                             const float* __restrict__ sWr, const float* __restrict__ sbr,
                             float* __restrict__ packed, int n) {
    __shared__ float ws[4096];
    __shared__ float bs[64];
    int t = threadIdx.x;
    for (int i = t; i < 1024; i += 256) {
        int k = i >> 4, j = i & 15;
        ws[k * 64 + j] = fWl[i];
        ws[k * 64 + 16 + j] = sWl[i];
        ws[k * 64 + 32 + j] = fWr[i];
        ws[k * 64 + 48 + j] = sWr[i];
    }
    if (t < 16) { bs[t] = fbl[t]; bs[16 + t] = sbl[t]; bs[32 + t] = fbr[t]; bs[48 + t] = sbr[t]; }
    __syncthreads();
    int rg = t >> 2, cg = (t & 3) << 4;
    int r0 = blockIdx.x * 256 + rg * 4;
    float acc[4][16];
#pragma unroll
    for (int r = 0; r < 4; ++r)
#pragma unroll
        for (int j = 0; j < 16; ++j) acc[r][j] = 0.f;
    for (int k0 = 0; k0 < 64; k0 += 4) {
        float hk[4][4];
#pragma unroll
        for (int r = 0; r < 4; ++r) {
            int gr = r0 + r;
            float4 v = (gr < n) ? *(const float4*)(h + (size_t)gr * 64 + k0)
                                : make_float4(0.f, 0.f, 0.f, 0.f);
            hk[r][0] = v.x; hk[r][1] = v.y; hk[r][2] = v.z; hk[r][3] = v.w;
        }
#pragma unroll
        for (int kk = 0; kk < 4; ++kk) {
            const float* wrow = ws + (k0 + kk) * 64 + cg;
#pragma unroll
            for (int r = 0; r < 4; ++r)
#pragma unroll
                for (int j = 0; j < 16; ++j) acc[r][j] += hk[r][kk] * wrow[j];
        }
    }
#pragma unroll
    for (int r = 0; r < 4; ++r) {
        int gr = r0 + r;
        if (gr < n) {
            float* o = packed + (size_t)gr * 64 + cg;
#pragma unroll
            for (int j = 0; j < 16; ++j) o[j] = acc[r][j] + bs[cg + j];
        }
    }
}

// ---------------- GATv2 attention, 64-feature layers ----------------
// one wave per dst node; lane = head*4 + channel. Online softmax, single pass.
__launch_bounds__(256)
__global__ void k_gat(const float* __restrict__ xl, const float* __restrict__ xr,
                      const int* __restrict__ row_ptr, const int* __restrict__ csr_src,
                      const float* __restrict__ csr_ea,
                      const float* __restrict__ We,   // [2,64]
                      const float* __restrict__ att,  // [16,4] flat
                      const float* __restrict__ bias, // [64]
                      float* __restrict__ out, int n, int relu) {
    int wave = (blockIdx.x * blockDim.x + threadIdx.x) >> 6;
    int lane = threadIdx.x & 63;
    if (wave >= n) return;
    const int d = wave;
    const int p0 = __builtin_amdgcn_readfirstlane(row_ptr[d]);
    const int p1 = __builtin_amdgcn_readfirstlane(row_ptr[d + 1]);
    const float we0 = We[lane], we1 = We[64 + lane];
    const float av = att[lane];
    const float xrv = xr[(size_t)d * 64 + lane];
    float mx = -3.0e38f, den = 0.f, acc = 0.f;
    int p = p0;
    for (; p + 2 <= p1; p += 2) {
        int s0 = csr_src[p], s1 = csr_src[p + 1];
        float2 e0 = *(const float2*)(csr_ea + 2 * (size_t)p);
        float2 e1 = *(const float2*)(csr_ea + 2 * (size_t)p + 2);
        float x0 = xl[(size_t)s0 * 64 + lane];
        float x1 = xl[(size_t)s1 * 64 + lane];
        float tv = lrelu(x0 + xrv + e0.x * we0 + e0.y * we1, 0.2f) * av;
        tv += __shfl_xor(tv, 1);
        tv += __shfl_xor(tv, 2);
        float nm = fmaxf(mx, tv);
        float sc = __expf(mx - nm), w = __expf(tv - nm);
        den = den * sc + w;
        acc = acc * sc + w * x0;
        mx = nm;
        tv = lrelu(x1 + xrv + e1.x * we0 + e1.y * we1, 0.2f) * av;
        tv += __shfl_xor(tv, 1);
        tv += __shfl_xor(tv, 2);
        nm = fmaxf(mx, tv);
        sc = __expf(mx - nm); w = __expf(tv - nm);
        den = den * sc + w;
        acc = acc * sc + w * x1;
        mx = nm;
    }
    if (p < p1) {
        int s0 = csr_src[p];
        float2 e0 = *(const float2*)(csr_ea + 2 * (size_t)p);
        float x0 = xl[(size_t)s0 * 64 + lane];
        float tv = lrelu(x0 + xrv + e0.x * we0 + e0.y * we1, 0.2f) * av;
        tv += __shfl_xor(tv, 1);
        tv += __shfl_xor(tv, 2);
        float nm = fmaxf(mx, tv);
        float sc = __expf(mx - nm), w = __expf(tv - nm);
        den = den * sc + w;
        acc = acc * sc + w * x0;
    }
    float o = acc / den + bias[lane];
    if (relu) o = lrelu(o, 0.01f);
    out[(size_t)d * 64 + lane] = o;
}

// ---------------- final two H=16,C=1 layers fused ----------------
// half-wave per dst: lanes 0-15 = f (-> fin), 16-31 = s (-> mus). Online softmax.
__launch_bounds__(256)
__global__ void k_gat_final(const float* __restrict__ packed,
                            const int* __restrict__ row_ptr, const int* __restrict__ csr_src,
                            const float* __restrict__ csr_ea,
                            const float* __restrict__ fWe, const float* __restrict__ sWe,
                            const float* __restrict__ fatt, const float* __restrict__ satt,
                            const float* __restrict__ fbias, const float* __restrict__ sbias,
                            float* __restrict__ fin, float* __restrict__ mus, int n) {
    int hw = (blockIdx.x * blockDim.x + threadIdx.x) >> 5;
    if (hw >= n) return;
    int l = threadIdx.x & 31;
    int hh = l & 15, sel = l >> 4;
    const int d = hw;
    const int p0 = row_ptr[d], p1 = row_ptr[d + 1];
    const float* We = sel ? sWe : fWe;
    float we0 = We[hh], we1 = We[16 + hh];
    float av = (sel ? satt : fatt)[hh];
    float xrv = packed[(size_t)d * 64 + 32 + sel * 16 + hh];
    int xli = sel * 16 + hh;
    float mx = -3.0e38f, den = 0.f, acc = 0.f;
    int p = p0;
    for (; p + 2 <= p1; p += 2) {
        int s0 = csr_src[p], s1 = csr_src[p + 1];
        float2 e0 = *(const float2*)(csr_ea + 2 * (size_t)p);
        float2 e1 = *(const float2*)(csr_ea + 2 * (size_t)p + 2);
        float x0 = packed[(size_t)s0 * 64 + xli];
        float x1 = packed[(size_t)s1 * 64 + xli];
        float t = lrelu(x0 + xrv + e0.x * we0 + e0.y * we1, 0.2f) * av;
        float nm = fmaxf(mx, t);
        float sc = __expf(mx - nm), w = __expf(t - nm);
        den = den * sc + w; acc = acc * sc + w * x0; mx = nm;
        t = lrelu(x1 + xrv + e1.x * we0 + e1.y * we1, 0.2f) * av;
        nm = fmaxf(mx, t);
        sc = __expf(mx - nm); w = __expf(t - nm);
        den = den * sc + w; acc = acc * sc + w * x1; mx = nm;
    }
    if (p < p1) {
        int s0 = csr_src[p];
        float2 e0 = *(const float2*)(csr_ea + 2 * (size_t)p);
        float x0 = packed[(size_t)s0 * 64 + xli];
        float t = lrelu(x0 + xrv + e0.x * we0 + e0.y * we1, 0.2f) * av;
        float nm = fmaxf(mx, t);
        float sc = __expf(mx - nm), w = __expf(t - nm);
        den = den * sc + w; acc = acc * sc + w * x0;
    }
    float val = acc / den;
#pragma unroll
    for (int w = 1; w < 16; w <<= 1) val += __shfl_xor(val, w);
    if ((threadIdx.x & 15) == 0) {
        float o = val * (1.f / 16.f) + (sel ? sbias[0] : fbias[0]);
        if (sel) mus[d] = o; else fin[d] = o;
    }
}

// ---------------- batchnorm ----------------

__global__ void k_bnstats(const float* __restrict__ h, double* __restrict__ stats, int n) {
    int c = threadIdx.x & 63;
    int s0 = blockIdx.x * (blockDim.x >> 6) + (threadIdx.x >> 6);
    int ns = gridDim.x * (blockDim.x >> 6);
    double s = 0.0, s2 = 0.0;
    for (int i = s0; i < n; i += ns) {
        float v = h[(size_t)i * 64 + c];
        s += v;
        s2 += (double)v * v;
    }
    atomicAdd(&stats[c], s);
    atomicAdd(&stats[64 + c], s2);
}

__global__ void k_bnapply(float* __restrict__ h, const double* __restrict__ stats,
                          const float* __restrict__ gamma, const float* __restrict__ beta, int n) {
    int idx = blockIdx.x * blockDim.x + threadIdx.x;
    if (idx >= n * 64) return;
    int c = idx & 63;
    double mu = stats[c] / n;
    double var = stats[64 + c] / n - mu * mu;
    float rs = (float)(1.0 / sqrt(var + 1e-5));
    float v = (h[idx] - (float)mu) * rs * gamma[c] + beta[c];
    h[idx] = lrelu(v, 0.01f);
}

// ---------------- graph-level mean over masked nodes ----------------

__global__ void k_sat_acc(const float* __restrict__ fin, const int* __restrict__ mask,
                          const int* __restrict__ batch,
                          float* __restrict__ sums, float* __restrict__ cnts, int n) {
    int i = blockIdx.x * blockDim.x + threadIdx.x;
    if (i >= n) return;
    if (mask[i] == 0) {
        int g = batch[i];
        atomicAdd(&sums[g], fin[i]);
        atomicAdd(&cnts[g], 1.f);
    }
}

__global__ void k_sat_fin(const float* __restrict__ sums, const float* __restrict__ cnts,
                          float* __restrict__ out, int g) {
    int i = threadIdx.x;
    if (i < g) out[i] = sums[i] / fmaxf(cnts[i], 1.f);
}

// ---------------- host ----------------

extern "C" void kernel_launch(void* const* d_in, const int* in_sizes, int n_in,
                              void* d_out, int out_size, void* d_ws, size_t ws_size,
                              hipStream_t stream) {
    const float* x = (const float*)d_in[0];
    const float* eat = (const float*)d_in[1];
    const int* ei = (const int*)d_in[2];
    const int* mask = (const int*)d_in[3];
    const int* batch = (const int*)d_in[4];
    const float* g0_Wl = (const float*)d_in[5];
    const float* g0_bl = (const float*)d_in[6];
    const float* g0_Wr = (const float*)d_in[7];
    const float* g0_br = (const float*)d_in[8];
    const float* g0_We = (const float*)d_in[9];
    const float* g0_att = (const float*)d_in[10];
    const float* g0_bias = (const float*)d_in[11];
    const float* bn_g = (const float*)d_in[12];
    const float* bn_b = (const float*)d_in[13];
    const float* m_Wl = (const float*)d_in[14];
    const float* m_bl = (const float*)d_in[15];
    const float* m_Wr = (const float*)d_in[16];
    const float* m_br = (const float*)d_in[17];
    const float* m_We = (const float*)d_in[18];
    const float* m_att = (const float*)d_in[19];
    const float* m_bias = (const float*)d_in[20];
    const float* f_Wl = (const float*)d_in[21];
    const float* f_bl = (const float*)d_in[22];
    const float* f_Wr = (const float*)d_in[23];
    const float* f_br = (const float*)d_in[24];
    const float* f_We = (const float*)d_in[25];
    const float* f_att = (const float*)d_in[26];
    const float* f_bias = (const float*)d_in[27];
    const float* s_Wl = (const float*)d_in[28];
    const float* s_bl = (const float*)d_in[29];
    const float* s_Wr = (const float*)d_in[30];
    const float* s_br = (const float*)d_in[31];
    const float* s_We = (const float*)d_in[32];
    const float* s_att = (const float*)d_in[33];
    const float* s_bias = (const float*)d_in[34];

    const int N = in_sizes[3];
    const int E = in_sizes[1] / 2;
    const int G = out_size - N;
    const int ITER = in_sizes[14] / 4096;
    const int ET = E + N;
    const int* srcp = ei;
    const int* dstp = ei + E;

    char* wsb = (char*)d_ws;
    size_t off = 0;
    auto alloc = [&](size_t b) { void* p = wsb + off; off = (off + b + 255) & ~(size_t)255; return p; };
    int* cnt = (int*)alloc((size_t)N * 4);
    float* esum = (float*)alloc((size_t)N * 8);
    int* fill = (int*)alloc((size_t)N * 4);
    double* stats = (double*)alloc(128 * 8);
    float* sums = (float*)alloc((size_t)G * 4);
    float* cnts = (float*)alloc((size_t)G * 4);
    size_t zero_bytes = off;
    int* row_ptr = (int*)alloc((size_t)(N + 1) * 4);
    int* csr_src = (int*)alloc((size_t)ET * 4);
    float* csr_ea = (float*)alloc((size_t)ET * 8);
    float* xl = (float*)alloc((size_t)N * 256);
    float* xr = (float*)alloc((size_t)N * 256);
    float* hbuf = (float*)alloc((size_t)N * 256);
    float* fin = (float*)alloc((size_t)N * 4);
    (void)ws_size; (void)n_in;

    float* outv = (float*)d_out;  // [0,N) = mus, [N,N+G) = sat

    hipMemsetAsync(d_ws, 0, zero_bytes, stream);
    const int tb = 256;
    k_degree<<<(E + tb - 1) / tb, tb, 0, stream>>>(dstp, eat, cnt, esum, E);
    k_rowptr<<<1, 1024, 0, stream>>>(cnt, row_ptr, N);
    k_scatter<<<(E + tb - 1) / tb, tb, 0, stream>>>(srcp, dstp, eat, row_ptr, fill, csr_src, csr_ea, E);
    k_selfloop<<<(N + tb - 1) / tb, tb, 0, stream>>>(row_ptr, cnt, esum, csr_src, csr_ea, N);

    k_proj0<<<(N * 64 + tb - 1) / tb, tb, 0, stream>>>(x, g0_Wl, g0_bl, g0_Wr, g0_br, xl, xr, N);
    k_gat<<<(N * 64 + tb - 1) / tb, tb, 0, stream>>>(xl, xr, row_ptr, csr_src, csr_ea,
                                                     g0_We, g0_att, g0_bias, hbuf, N, 0);
    k_bnstats<<<128, 256, 0, stream>>>(hbuf, stats, N);
    k_bnapply<<<(N * 64 + tb - 1) / tb, tb, 0, stream>>>(hbuf, stats, bn_g, bn_b, N);

    dim3 gp((N + 255) / 256, 2);
    for (int l = 0; l < ITER; ++l) {
        k_proj64_dual<<<gp, 256, 0, stream>>>(hbuf, m_Wl + (size_t)l * 4096, m_bl + l * 64,
                                              m_Wr + (size_t)l * 4096, m_br + l * 64, xl, xr, N);
        k_gat<<<(N * 64 + tb - 1) / tb, tb, 0, stream>>>(xl, xr, row_ptr, csr_src, csr_ea,
                                                         m_We + l * 128, m_att + l * 64,
                                                         m_bias + l * 64, hbuf, N, 1);
    }
    k_proj_final<<<(N + 255) / 256, 256, 0, stream>>>(hbuf, f_Wl, f_bl, f_Wr, f_br,
                                                      s_Wl, s_bl, s_Wr, s_br, xl, N);
    k_gat_final<<<(N * 32 + tb - 1) / tb, tb, 0, stream>>>(xl, row_ptr, csr_src, csr_ea,
                                                           f_We, s_We, f_att, s_att,
                                                           f_bias, s_bias, fin, outv, N);
    k_sat_acc<<<(N + tb - 1) / tb, tb, 0, stream>>>(fin, mask, batch, sums, cnts, N);
    k_sat_fin<<<1, 64, 0, stream>>>(sums, cnts, outv + N, G);
}

// Round 3
// 838.397 us; speedup vs baseline: 2.0394x; 1.1364x over previous
//
#include <hip/hip_runtime.h>

// GATv2 stack on MI355X. fp32 throughout (no fp32 MFMA on CDNA4 -> vector ALU).
// R2: wave-segmented reduction for graph mean (kills atomic serialization);
// k_gat unroll-4 with dual independent online-softmax accumulators.

static __device__ __forceinline__ float lrelu(float x, float s) {
    return x > 0.f ? x : s * x;
}

// ---------------- graph build ----------------

__global__ void k_degree(const int* __restrict__ dst, const float* __restrict__ ea,
                         int* __restrict__ cnt, float* __restrict__ esum, int E) {
    int e = blockIdx.x * blockDim.x + threadIdx.x;
    if (e >= E) return;
    int d = dst[e];
    atomicAdd(&cnt[d], 1);
    atomicAdd(&esum[2 * d], ea[2 * e]);
    atomicAdd(&esum[2 * d + 1], ea[2 * e + 1]);
}

__launch_bounds__(1024)
__global__ void k_rowptr(const int* __restrict__ cnt, int* __restrict__ row_ptr, int n) {
    __shared__ int tot[1024];
    int t = threadIdx.x;
    int chunk = (n + 1023) >> 10;
    int b = min(t * chunk, n), e = min(b + chunk, n);
    int s = 0;
    for (int i = b; i < e; ++i) s += cnt[i] + 1;
    tot[t] = s;
    __syncthreads();
    for (int off = 1; off < 1024; off <<= 1) {
        int v = (t >= off) ? tot[t - off] : 0;
        __syncthreads();
        tot[t] += v;
        __syncthreads();
    }
    int run = (t > 0) ? tot[t - 1] : 0;
    for (int i = b; i < e; ++i) { row_ptr[i] = run; run += cnt[i] + 1; }
    if (t == 1023) row_ptr[n] = run;
}

__global__ void k_scatter(const int* __restrict__ src, const int* __restrict__ dst,
                          const float* __restrict__ ea,
                          const int* __restrict__ row_ptr, int* __restrict__ fill,
                          int* __restrict__ csr_src, float* __restrict__ csr_ea, int E) {
    int e = blockIdx.x * blockDim.x + threadIdx.x;
    if (e >= E) return;
    int d = dst[e];
    int pos = row_ptr[d] + atomicAdd(&fill[d], 1);
    csr_src[pos] = src[e];
    csr_ea[2 * (size_t)pos] = ea[2 * (size_t)e];
    csr_ea[2 * (size_t)pos + 1] = ea[2 * (size_t)e + 1];
}

__global__ void k_selfloop(const int* __restrict__ row_ptr, const int* __restrict__ cnt,
                           const float* __restrict__ esum,
                           int* __restrict__ csr_src, float* __restrict__ csr_ea, int n) {
    int i = blockIdx.x * blockDim.x + threadIdx.x;
    if (i >= n) return;
    int p = row_ptr[i + 1] - 1;
    csr_src[p] = i;
    float c = fmaxf((float)cnt[i], 1.f);
    csr_ea[2 * (size_t)p] = esum[2 * i] / c;
    csr_ea[2 * (size_t)p + 1] = esum[2 * i + 1] / c;
}

// ---------------- projections ----------------

__global__ void k_proj0(const float* __restrict__ x,
                        const float* __restrict__ Wl, const float* __restrict__ bl,
                        const float* __restrict__ Wr, const float* __restrict__ br,
                        float* __restrict__ xl, float* __restrict__ xr, int n) {
    int idx = blockIdx.x * blockDim.x + threadIdx.x;
    if (idx >= n * 64) return;
    int i = idx >> 6, c = idx & 63;
    float x0 = x[2 * i], x1 = x[2 * i + 1];
    xl[idx] = x0 * Wl[c] + x1 * Wl[64 + c] + bl[c];
    xr[idx] = x0 * Wr[c] + x1 * Wr[64 + c] + br[c];
}

__launch_bounds__(256)
__global__ void k_proj64_dual(const float* __restrict__ h,
                              const float* __restrict__ Wl, const float* __restrict__ bl,
                              const float* __restrict__ Wr, const float* __restrict__ br,
                              float* __restrict__ xl, float* __restrict__ xr, int n) {
    __shared__ float ws[4096];
    const float* W = blockIdx.y ? Wr : Wl;
    const float* bias = blockIdx.y ? br : bl;
    float* out = blockIdx.y ? xr : xl;
    int t = threadIdx.x;
    for (int i = t; i < 4096; i += 256) ws[i] = W[i];
    __syncthreads();
    int rg = t >> 2, cg = (t & 3) << 4;
    int r0 = blockIdx.x * 256 + rg * 4;
    float acc[4][16];
#pragma unroll
    for (int r = 0; r < 4; ++r)
#pragma unroll
        for (int j = 0; j < 16; ++j) acc[r][j] = 0.f;
    for (int k0 = 0; k0 < 64; k0 += 4) {
        float hk[4][4];
#pragma unroll
        for (int r = 0; r < 4; ++r) {
            int gr = r0 + r;
            float4 v = (gr < n) ? *(const float4*)(h + (size_t)gr * 64 + k0)
                                : make_float4(0.f, 0.f, 0.f, 0.f);
            hk[r][0] = v.x; hk[r][1] = v.y; hk[r][2] = v.z; hk[r][3] = v.w;
        }
#pragma unroll
        for (int kk = 0; kk < 4; ++kk) {
            const float* wrow = ws + (k0 + kk) * 64 + cg;
#pragma unroll
            for (int r = 0; r < 4; ++r)
#pragma unroll
                for (int j = 0; j < 16; ++j) acc[r][j] += hk[r][kk] * wrow[j];
        }
    }
#pragma unroll
    for (int r = 0; r < 4; ++r) {
        int gr = r0 + r;
        if (gr < n) {
            float* o = out + (size_t)gr * 64 + cg;
#pragma unroll
            for (int j = 0; j < 16; ++j) o[j] = acc[r][j] + bias[cg + j];
        }
    }
}

// final projections fused: packed[i][0:16)=f_xl, [16:32)=s_xl, [32:48)=f_xr, [48:64)=s_xr
__launch_bounds__(256)
__global__ void k_proj_final(const float* __restrict__ h,
                             const float* __restrict__ fWl, const float* __restrict__ fbl,
                             const float* __restrict__ fWr, const float* __restrict__ fbr,
                             const float* __restrict__ sWl, const float* __restrict__ sbl,
                             const float* __restrict__ sWr, const float* __restrict__ sbr,
                             float* __restrict__ packed, int n) {
    __shared__ float ws[4096];
    __shared__ float bs[64];
    int t = threadIdx.x;
    for (int i = t; i < 1024; i += 256) {
        int k = i >> 4, j = i & 15;
        ws[k * 64 + j] = fWl[i];
        ws[k * 64 + 16 + j] = sWl[i];
        ws[k * 64 + 32 + j] = fWr[i];
        ws[k * 64 + 48 + j] = sWr[i];
    }
    if (t < 16) { bs[t] = fbl[t]; bs[16 + t] = sbl[t]; bs[32 + t] = fbr[t]; bs[48 + t] = sbr[t]; }
    __syncthreads();
    int rg = t >> 2, cg = (t & 3) << 4;
    int r0 = blockIdx.x * 256 + rg * 4;
    float acc[4][16];
#pragma unroll
    for (int r = 0; r < 4; ++r)
#pragma unroll
        for (int j = 0; j < 16; ++j) acc[r][j] = 0.f;
    for (int k0 = 0; k0 < 64; k0 += 4) {
        float hk[4][4];
#pragma unroll
        for (int r = 0; r < 4; ++r) {
            int gr = r0 + r;
            float4 v = (gr < n) ? *(const float4*)(h + (size_t)gr * 64 + k0)
                                : make_float4(0.f, 0.f, 0.f, 0.f);
            hk[r][0] = v.x; hk[r][1] = v.y; hk[r][2] = v.z; hk[r][3] = v.w;
        }
#pragma unroll
        for (int kk = 0; kk < 4; ++kk) {
            const float* wrow = ws + (k0 + kk) * 64 + cg;
#pragma unroll
            for (int r = 0; r < 4; ++r)
#pragma unroll
                for (int j = 0; j < 16; ++j) acc[r][j] += hk[r][kk] * wrow[j];
        }
    }
#pragma unroll
    for (int r = 0; r < 4; ++r) {
        int gr = r0 + r;
        if (gr < n) {
            float* o = packed + (size_t)gr * 64 + cg;
#pragma unroll
            for (int j = 0; j < 16; ++j) o[j] = acc[r][j] + bs[cg + j];
        }
    }
}

// ---------------- GATv2 attention, 64-feature layers ----------------
// one wave per dst node; lane = head*4 + channel. Online softmax, single pass,
// unroll-4 with two independent accumulator sets (even/odd) for ILP.
__launch_bounds__(256)
__global__ void k_gat(const float* __restrict__ xl, const float* __restrict__ xr,
                      const int* __restrict__ row_ptr, const int* __restrict__ csr_src,
                      const float* __restrict__ csr_ea,
                      const float* __restrict__ We,   // [2,64]
                      const float* __restrict__ att,  // [16,4] flat
                      const float* __restrict__ bias, // [64]
                      float* __restrict__ out, int n, int relu) {
    int wave = (blockIdx.x * blockDim.x + threadIdx.x) >> 6;
    int lane = threadIdx.x & 63;
    if (wave >= n) return;
    const int d = wave;
    const int p0 = __builtin_amdgcn_readfirstlane(row_ptr[d]);
    const int p1 = __builtin_amdgcn_readfirstlane(row_ptr[d + 1]);
    const float we0 = We[lane], we1 = We[64 + lane];
    const float av = att[lane];
    const float xrv = xr[(size_t)d * 64 + lane];

    float mx0 = -3.0e38f, den0 = 0.f, acc0 = 0.f;
    float mx1 = -3.0e38f, den1 = 0.f, acc1 = 0.f;

    auto step = [&](float xv, float2 ea, float& mx, float& den, float& acc) {
        float tv = lrelu(xv + xrv + ea.x * we0 + ea.y * we1, 0.2f) * av;
        tv += __shfl_xor(tv, 1);
        tv += __shfl_xor(tv, 2);
        float nm = fmaxf(mx, tv);
        float sc = __expf(mx - nm), w = __expf(tv - nm);
        den = den * sc + w;
        acc = acc * sc + w * xv;
        mx = nm;
    };

    int p = p0;
    for (; p + 4 <= p1; p += 4) {
        int s0 = csr_src[p], s1 = csr_src[p + 1], s2 = csr_src[p + 2], s3 = csr_src[p + 3];
        float2 e0 = *(const float2*)(csr_ea + 2 * (size_t)p);
        float2 e1 = *(const float2*)(csr_ea + 2 * (size_t)p + 2);
        float2 e2 = *(const float2*)(csr_ea + 2 * (size_t)p + 4);
        float2 e3 = *(const float2*)(csr_ea + 2 * (size_t)p + 6);
        float x0 = xl[(size_t)s0 * 64 + lane];
        float x1 = xl[(size_t)s1 * 64 + lane];
        float x2 = xl[(size_t)s2 * 64 + lane];
        float x3 = xl[(size_t)s3 * 64 + lane];
        step(x0, e0, mx0, den0, acc0);
        step(x1, e1, mx1, den1, acc1);
        step(x2, e2, mx0, den0, acc0);
        step(x3, e3, mx1, den1, acc1);
    }
    for (; p < p1; ++p) {
        int s0 = csr_src[p];
        float2 e0 = *(const float2*)(csr_ea + 2 * (size_t)p);
        float x0 = xl[(size_t)s0 * 64 + lane];
        step(x0, e0, mx0, den0, acc0);
    }
    // merge the two accumulator sets
    float nm = fmaxf(mx0, mx1);
    float sc0 = __expf(mx0 - nm), sc1 = __expf(mx1 - nm);
    float den = den0 * sc0 + den1 * sc1;
    float acc = acc0 * sc0 + acc1 * sc1;

    float o = acc / den + bias[lane];
    if (relu) o = lrelu(o, 0.01f);
    out[(size_t)d * 64 + lane] = o;
}

// ---------------- final two H=16,C=1 layers fused ----------------
// half-wave per dst: lanes 0-15 = f (-> fin), 16-31 = s (-> mus). Online softmax.
__launch_bounds__(256)
__global__ void k_gat_final(const float* __restrict__ packed,
                            const int* __restrict__ row_ptr, const int* __restrict__ csr_src,
                            const float* __restrict__ csr_ea,
                            const float* __restrict__ fWe, const float* __restrict__ sWe,
                            const float* __restrict__ fatt, const float* __restrict__ satt,
                            const float* __restrict__ fbias, const float* __restrict__ sbias,
                            float* __restrict__ fin, float* __restrict__ mus, int n) {
    int hw = (blockIdx.x * blockDim.x + threadIdx.x) >> 5;
    if (hw >= n) return;
    int l = threadIdx.x & 31;
    int hh = l & 15, sel = l >> 4;
    const int d = hw;
    const int p0 = row_ptr[d], p1 = row_ptr[d + 1];
    const float* We = sel ? sWe : fWe;
    float we0 = We[hh], we1 = We[16 + hh];
    float av = (sel ? satt : fatt)[hh];
    float xrv = packed[(size_t)d * 64 + 32 + sel * 16 + hh];
    int xli = sel * 16 + hh;

    float mx0 = -3.0e38f, den0 = 0.f, acc0 = 0.f;
    float mx1 = -3.0e38f, den1 = 0.f, acc1 = 0.f;

    auto step = [&](float xv, float2 ea, float& mx, float& den, float& acc) {
        float t = lrelu(xv + xrv + ea.x * we0 + ea.y * we1, 0.2f) * av;
        float nm = fmaxf(mx, t);
        float sc = __expf(mx - nm), w = __expf(t - nm);
        den = den * sc + w;
        acc = acc * sc + w * xv;
        mx = nm;
    };

    int p = p0;
    for (; p + 4 <= p1; p += 4) {
        int s0 = csr_src[p], s1 = csr_src[p + 1], s2 = csr_src[p + 2], s3 = csr_src[p + 3];
        float2 e0 = *(const float2*)(csr_ea + 2 * (size_t)p);
        float2 e1 = *(const float2*)(csr_ea + 2 * (size_t)p + 2);
        float2 e2 = *(const float2*)(csr_ea + 2 * (size_t)p + 4);
        float2 e3 = *(const float2*)(csr_ea + 2 * (size_t)p + 6);
        float x0 = packed[(size_t)s0 * 64 + xli];
        float x1 = packed[(size_t)s1 * 64 + xli];
        float x2 = packed[(size_t)s2 * 64 + xli];
        float x3 = packed[(size_t)s3 * 64 + xli];
        step(x0, e0, mx0, den0, acc0);
        step(x1, e1, mx1, den1, acc1);
        step(x2, e2, mx0, den0, acc0);
        step(x3, e3, mx1, den1, acc1);
    }
    for (; p < p1; ++p) {
        int s0 = csr_src[p];
        float2 e0 = *(const float2*)(csr_ea + 2 * (size_t)p);
        float x0 = packed[(size_t)s0 * 64 + xli];
        step(x0, e0, mx0, den0, acc0);
    }
    float nm = fmaxf(mx0, mx1);
    float sc0 = __expf(mx0 - nm), sc1 = __expf(mx1 - nm);
    float val = (acc0 * sc0 + acc1 * sc1) / (den0 * sc0 + den1 * sc1);
#pragma unroll
    for (int w = 1; w < 16; w <<= 1) val += __shfl_xor(val, w);
    if ((threadIdx.x & 15) == 0) {
        float o = val * (1.f / 16.f) + (sel ? sbias[0] : fbias[0]);
        if (sel) mus[d] = o; else fin[d] = o;
    }
}

// ---------------- batchnorm ----------------

__global__ void k_bnstats(const float* __restrict__ h, double* __restrict__ stats, int n) {
    int c = threadIdx.x & 63;
    int s0 = blockIdx.x * (blockDim.x >> 6) + (threadIdx.x >> 6);
    int ns = gridDim.x * (blockDim.x >> 6);
    double s = 0.0, s2 = 0.0;
    for (int i = s0; i < n; i += ns) {
        float v = h[(size_t)i * 64 + c];
        s += v;
        s2 += (double)v * v;
    }
    atomicAdd(&stats[c], s);
    atomicAdd(&stats[64 + c], s2);
}

__global__ void k_bnapply(float* __restrict__ h, const double* __restrict__ stats,
                          const float* __restrict__ gamma, const float* __restrict__ beta, int n) {
    int idx = blockIdx.x * blockDim.x + threadIdx.x;
    if (idx >= n * 64) return;
    int c = idx & 63;
    double mu = stats[c] / n;
    double var = stats[64 + c] / n - mu * mu;
    float rs = (float)(1.0 / sqrt(var + 1e-5));
    float v = (h[idx] - (float)mu) * rs * gamma[c] + beta[c];
    h[idx] = lrelu(v, 0.01f);
}

// ---------------- graph-level mean over masked nodes ----------------
// batch is sorted -> wave-level segmented reduction, one atomic per run head.
__global__ void k_sat_acc(const float* __restrict__ fin, const int* __restrict__ mask,
                          const int* __restrict__ batch,
                          float* __restrict__ sums, float* __restrict__ cnts, int n) {
    int i = blockIdx.x * blockDim.x + threadIdx.x;
    int lane = threadIdx.x & 63;
    int g = (i < n) ? batch[i] : -1;
    float c = (i < n && mask[i] == 0) ? 1.f : 0.f;
    float v = (c > 0.f) ? fin[i] : 0.f;
    // segmented reduction over contiguous equal-g runs within the wave
#pragma unroll
    for (int off = 1; off < 64; off <<= 1) {
        float v2 = __shfl_down(v, off);
        float c2 = __shfl_down(c, off);
        int g2 = __shfl_down(g, off);
        if (lane + off < 64 && g2 == g) { v += v2; c += c2; }
    }
    int gprev = __shfl_up(g, 1);
    bool head = (lane == 0) || (gprev != g);
    if (head && g >= 0 && c > 0.f) {
        atomicAdd(&sums[g], v);
        atomicAdd(&cnts[g], c);
    }
}

__global__ void k_sat_fin(const float* __restrict__ sums, const float* __restrict__ cnts,
                          float* __restrict__ out, int g) {
    int i = threadIdx.x;
    if (i < g) out[i] = sums[i] / fmaxf(cnts[i], 1.f);
}

// ---------------- host ----------------

extern "C" void kernel_launch(void* const* d_in, const int* in_sizes, int n_in,
                              void* d_out, int out_size, void* d_ws, size_t ws_size,
                              hipStream_t stream) {
    const float* x = (const float*)d_in[0];
    const float* eat = (const float*)d_in[1];
    const int* ei = (const int*)d_in[2];
    const int* mask = (const int*)d_in[3];
    const int* batch = (const int*)d_in[4];
    const float* g0_Wl = (const float*)d_in[5];
    const float* g0_bl = (const float*)d_in[6];
    const float* g0_Wr = (const float*)d_in[7];
    const float* g0_br = (const float*)d_in[8];
    const float* g0_We = (const float*)d_in[9];
    const float* g0_att = (const float*)d_in[10];
    const float* g0_bias = (const float*)d_in[11];
    const float* bn_g = (const float*)d_in[12];
    const float* bn_b = (const float*)d_in[13];
    const float* m_Wl = (const float*)d_in[14];
    const float* m_bl = (const float*)d_in[15];
    const float* m_Wr = (const float*)d_in[16];
    const float* m_br = (const float*)d_in[17];
    const float* m_We = (const float*)d_in[18];
    const float* m_att = (const float*)d_in[19];
    const float* m_bias = (const float*)d_in[20];
    const float* f_Wl = (const float*)d_in[21];
    const float* f_bl = (const float*)d_in[22];
    const float* f_Wr = (const float*)d_in[23];
    const float* f_br = (const float*)d_in[24];
    const float* f_We = (const float*)d_in[25];
    const float* f_att = (const float*)d_in[26];
    const float* f_bias = (const float*)d_in[27];
    const float* s_Wl = (const float*)d_in[28];
    const float* s_bl = (const float*)d_in[29];
    const float* s_Wr = (const float*)d_in[30];
    const float* s_br = (const float*)d_in[31];
    const float* s_We = (const float*)d_in[32];
    const float* s_att = (const float*)d_in[33];
    const float* s_bias = (const float*)d_in[34];

    const int N = in_sizes[3];
    const int E = in_sizes[1] / 2;
    const int G = out_size - N;
    const int ITER = in_sizes[14] / 4096;
    const int ET = E + N;
    const int* srcp = ei;
    const int* dstp = ei + E;

    char* wsb = (char*)d_ws;
    size_t off = 0;
    auto alloc = [&](size_t b) { void* p = wsb + off; off = (off + b + 255) & ~(size_t)255; return p; };
    int* cnt = (int*)alloc((size_t)N * 4);
    float* esum = (float*)alloc((size_t)N * 8);
    int* fill = (int*)alloc((size_t)N * 4);
    double* stats = (double*)alloc(128 * 8);
    float* sums = (float*)alloc((size_t)G * 4);
    float* cnts = (float*)alloc((size_t)G * 4);
    size_t zero_bytes = off;
    int* row_ptr = (int*)alloc((size_t)(N + 1) * 4);
    int* csr_src = (int*)alloc((size_t)ET * 4);
    float* csr_ea = (float*)alloc((size_t)ET * 8);
    float* xl = (float*)alloc((size_t)N * 256);
    float* xr = (float*)alloc((size_t)N * 256);
    float* hbuf = (float*)alloc((size_t)N * 256);
    float* fin = (float*)alloc((size_t)N * 4);
    (void)ws_size; (void)n_in;

    float* outv = (float*)d_out;  // [0,N) = mus, [N,N+G) = sat

    hipMemsetAsync(d_ws, 0, zero_bytes, stream);
    const int tb = 256;
    k_degree<<<(E + tb - 1) / tb, tb, 0, stream>>>(dstp, eat, cnt, esum, E);
    k_rowptr<<<1, 1024, 0, stream>>>(cnt, row_ptr, N);
    k_scatter<<<(E + tb - 1) / tb, tb, 0, stream>>>(srcp, dstp, eat, row_ptr, fill, csr_src, csr_ea, E);
    k_selfloop<<<(N + tb - 1) / tb, tb, 0, stream>>>(row_ptr, cnt, esum, csr_src, csr_ea, N);

    k_proj0<<<(N * 64 + tb - 1) / tb, tb, 0, stream>>>(x, g0_Wl, g0_bl, g0_Wr, g0_br, xl, xr, N);
    k_gat<<<(N * 64 + tb - 1) / tb, tb, 0, stream>>>(xl, xr, row_ptr, csr_src, csr_ea,
                                                     g0_We, g0_att, g0_bias, hbuf, N, 0);
    k_bnstats<<<128, 256, 0, stream>>>(hbuf, stats, N);
    k_bnapply<<<(N * 64 + tb - 1) / tb, tb, 0, stream>>>(hbuf, stats, bn_g, bn_b, N);

    dim3 gp((N + 255) / 256, 2);
    for (int l = 0; l < ITER; ++l) {
        k_proj64_dual<<<gp, 256, 0, stream>>>(hbuf, m_Wl + (size_t)l * 4096, m_bl + l * 64,
                                              m_Wr + (size_t)l * 4096, m_br + l * 64, xl, xr, N);
        k_gat<<<(N * 64 + tb - 1) / tb, tb, 0, stream>>>(xl, xr, row_ptr, csr_src, csr_ea,
                                                         m_We + l * 128, m_att + l * 64,
                                                         m_bias + l * 64, hbuf, N, 1);
    }
    k_proj_final<<<(N + 255) / 256, 256, 0, stream>>>(hbuf, f_Wl, f_bl, f_Wr, f_br,
                                                      s_Wl, s_bl, s_Wr, s_br, xl, N);
    k_gat_final<<<(N * 32 + tb - 1) / tb, tb, 0, stream>>>(xl, row_ptr, csr_src, csr_ea,
                                                           f_We, s_We, f_att, s_att,
                                                           f_bias, s_bias, fin, outv, N);
    k_sat_acc<<<(N + tb - 1) / tb, tb, 0, stream>>>(fin, mask, batch, sums, cnts, N);
    k_sat_fin<<<1, 64, 0, stream>>>(sums, cnts, outv + N, G);
}

// Round 4
// 832.875 us; speedup vs baseline: 2.0529x; 1.0066x over previous
//
#include <hip/hip_runtime.h>

// GATv2 stack on MI355X. fp32 throughout (no fp32 MFMA on CDNA4 -> vector ALU).
// R3: graph build with 1 atomic/edge (rank trick; self-loop attr mean computed
// from the contiguous CSR segment, not via float atomics); predicated unroll-4
// edge loops in the attention kernels (no serial scalar tail).

static __device__ __forceinline__ float lrelu(float x, float s) {
    return x > 0.f ? x : s * x;
}

// ---------------- graph build ----------------

// one atomic per edge; rank = arrival order within dst segment
__global__ void k_degree(const int* __restrict__ dst, int* __restrict__ cnt,
                         int* __restrict__ rank, int E) {
    int e = blockIdx.x * blockDim.x + threadIdx.x;
    if (e >= E) return;
    rank[e] = atomicAdd(&cnt[dst[e]], 1);
}

__launch_bounds__(1024)
__global__ void k_rowptr(const int* __restrict__ cnt, int* __restrict__ row_ptr, int n) {
    __shared__ int tot[1024];
    int t = threadIdx.x;
    int chunk = (n + 1023) >> 10;
    int b = min(t * chunk, n), e = min(b + chunk, n);
    int s = 0;
    for (int i = b; i < e; ++i) s += cnt[i] + 1;
    tot[t] = s;
    __syncthreads();
    for (int off = 1; off < 1024; off <<= 1) {
        int v = (t >= off) ? tot[t - off] : 0;
        __syncthreads();
        tot[t] += v;
        __syncthreads();
    }
    int run = (t > 0) ? tot[t - 1] : 0;
    for (int i = b; i < e; ++i) { row_ptr[i] = run; run += cnt[i] + 1; }
    if (t == 1023) row_ptr[n] = run;
}

// no atomics: position = row_ptr[dst] + rank
__global__ void k_scatter(const int* __restrict__ src, const int* __restrict__ dst,
                          const float* __restrict__ ea, const int* __restrict__ rank,
                          const int* __restrict__ row_ptr,
                          int* __restrict__ csr_src, float* __restrict__ csr_ea, int E) {
    int e = blockIdx.x * blockDim.x + threadIdx.x;
    if (e >= E) return;
    int pos = row_ptr[dst[e]] + rank[e];
    csr_src[pos] = src[e];
    csr_ea[2 * (size_t)pos] = ea[2 * (size_t)e];
    csr_ea[2 * (size_t)pos + 1] = ea[2 * (size_t)e + 1];
}

// self loop in last slot of each segment; attr = mean of the (contiguous) segment
__global__ void k_selfloop(const int* __restrict__ row_ptr,
                           int* __restrict__ csr_src, float* __restrict__ csr_ea, int n) {
    int i = blockIdx.x * blockDim.x + threadIdx.x;
    if (i >= n) return;
    int p0 = row_ptr[i], p1 = row_ptr[i + 1];
    float s0 = 0.f, s1 = 0.f;
    for (int p = p0; p < p1 - 1; ++p) {
        s0 += csr_ea[2 * (size_t)p];
        s1 += csr_ea[2 * (size_t)p + 1];
    }
    float c = fmaxf((float)(p1 - 1 - p0), 1.f);
    csr_src[p1 - 1] = i;
    csr_ea[2 * (size_t)(p1 - 1)] = s0 / c;
    csr_ea[2 * (size_t)(p1 - 1) + 1] = s1 / c;
}

// ---------------- projections ----------------

__global__ void k_proj0(const float* __restrict__ x,
                        const float* __restrict__ Wl, const float* __restrict__ bl,
                        const float* __restrict__ Wr, const float* __restrict__ br,
                        float* __restrict__ xl, float* __restrict__ xr, int n) {
    int idx = blockIdx.x * blockDim.x + threadIdx.x;
    if (idx >= n * 64) return;
    int i = idx >> 6, c = idx & 63;
    float x0 = x[2 * i], x1 = x[2 * i + 1];
    xl[idx] = x0 * Wl[c] + x1 * Wl[64 + c] + bl[c];
    xr[idx] = x0 * Wr[c] + x1 * Wr[64 + c] + br[c];
}

__launch_bounds__(256)
__global__ void k_proj64_dual(const float* __restrict__ h,
                              const float* __restrict__ Wl, const float* __restrict__ bl,
                              const float* __restrict__ Wr, const float* __restrict__ br,
                              float* __restrict__ xl, float* __restrict__ xr, int n) {
    __shared__ float ws[4096];
    const float* W = blockIdx.y ? Wr : Wl;
    const float* bias = blockIdx.y ? br : bl;
    float* out = blockIdx.y ? xr : xl;
    int t = threadIdx.x;
    for (int i = t; i < 4096; i += 256) ws[i] = W[i];
    __syncthreads();
    int rg = t >> 2, cg = (t & 3) << 4;
    int r0 = blockIdx.x * 256 + rg * 4;
    float acc[4][16];
#pragma unroll
    for (int r = 0; r < 4; ++r)
#pragma unroll
        for (int j = 0; j < 16; ++j) acc[r][j] = 0.f;
    for (int k0 = 0; k0 < 64; k0 += 4) {
        float hk[4][4];
#pragma unroll
        for (int r = 0; r < 4; ++r) {
            int gr = r0 + r;
            float4 v = (gr < n) ? *(const float4*)(h + (size_t)gr * 64 + k0)
                                : make_float4(0.f, 0.f, 0.f, 0.f);
            hk[r][0] = v.x; hk[r][1] = v.y; hk[r][2] = v.z; hk[r][3] = v.w;
        }
#pragma unroll
        for (int kk = 0; kk < 4; ++kk) {
            const float* wrow = ws + (k0 + kk) * 64 + cg;
#pragma unroll
            for (int r = 0; r < 4; ++r)
#pragma unroll
                for (int j = 0; j < 16; ++j) acc[r][j] += hk[r][kk] * wrow[j];
        }
    }
#pragma unroll
    for (int r = 0; r < 4; ++r) {
        int gr = r0 + r;
        if (gr < n) {
            float* o = out + (size_t)gr * 64 + cg;
#pragma unroll
            for (int j = 0; j < 16; ++j) o[j] = acc[r][j] + bias[cg + j];
        }
    }
}

// final projections fused: packed[i][0:16)=f_xl, [16:32)=s_xl, [32:48)=f_xr, [48:64)=s_xr
__launch_bounds__(256)
__global__ void k_proj_final(const float* __restrict__ h,
                             const float* __restrict__ fWl, const float* __restrict__ fbl,
                             const float* __restrict__ fWr, const float* __restrict__ fbr,
                             const float* __restrict__ sWl, const float* __restrict__ sbl,
                             const float* __restrict__ sWr, const float* __restrict__ sbr,
                             float* __restrict__ packed, int n) {
    __shared__ float ws[4096];
    __shared__ float bs[64];
    int t = threadIdx.x;
    for (int i = t; i < 1024; i += 256) {
        int k = i >> 4, j = i & 15;
        ws[k * 64 + j] = fWl[i];
        ws[k * 64 + 16 + j] = sWl[i];
        ws[k * 64 + 32 + j] = fWr[i];
        ws[k * 64 + 48 + j] = sWr[i];
    }
    if (t < 16) { bs[t] = fbl[t]; bs[16 + t] = sbl[t]; bs[32 + t] = fbr[t]; bs[48 + t] = sbr[t]; }
    __syncthreads();
    int rg = t >> 2, cg = (t & 3) << 4;
    int r0 = blockIdx.x * 256 + rg * 4;
    float acc[4][16];
#pragma unroll
    for (int r = 0; r < 4; ++r)
#pragma unroll
        for (int j = 0; j < 16; ++j) acc[r][j] = 0.f;
    for (int k0 = 0; k0 < 64; k0 += 4) {
        float hk[4][4];
#pragma unroll
        for (int r = 0; r < 4; ++r) {
            int gr = r0 + r;
            float4 v = (gr < n) ? *(const float4*)(h + (size_t)gr * 64 + k0)
                                : make_float4(0.f, 0.f, 0.f, 0.f);
            hk[r][0] = v.x; hk[r][1] = v.y; hk[r][2] = v.z; hk[r][3] = v.w;
        }
#pragma unroll
        for (int kk = 0; kk < 4; ++kk) {
            const float* wrow = ws + (k0 + kk) * 64 + cg;
#pragma unroll
            for (int r = 0; r < 4; ++r)
#pragma unroll
                for (int j = 0; j < 16; ++j) acc[r][j] += hk[r][kk] * wrow[j];
        }
    }
#pragma unroll
    for (int r = 0; r < 4; ++r) {
        int gr = r0 + r;
        if (gr < n) {
            float* o = packed + (size_t)gr * 64 + cg;
#pragma unroll
            for (int j = 0; j < 16; ++j) o[j] = acc[r][j] + bs[cg + j];
        }
    }
}

// ---------------- GATv2 attention, 64-feature layers ----------------
// one wave per dst node; lane = head*4 + channel. Online softmax, single pass,
// predicated unroll-4 (masked logit = -inf), two independent accumulator chains.
__launch_bounds__(256)
__global__ void k_gat(const float* __restrict__ xl, const float* __restrict__ xr,
                      const int* __restrict__ row_ptr, const int* __restrict__ csr_src,
                      const float* __restrict__ csr_ea,
                      const float* __restrict__ We,   // [2,64]
                      const float* __restrict__ att,  // [16,4] flat
                      const float* __restrict__ bias, // [64]
                      float* __restrict__ out, int n, int relu) {
    int wave = (blockIdx.x * blockDim.x + threadIdx.x) >> 6;
    int lane = threadIdx.x & 63;
    if (wave >= n) return;
    const int d = wave;
    const int p0 = __builtin_amdgcn_readfirstlane(row_ptr[d]);
    const int p1 = __builtin_amdgcn_readfirstlane(row_ptr[d + 1]);
    const float we0 = We[lane], we1 = We[64 + lane];
    const float av = att[lane];
    const float xrv = xr[(size_t)d * 64 + lane];

    float mx0 = -3.0e38f, den0 = 0.f, acc0 = 0.f;
    float mx1 = -3.0e38f, den1 = 0.f, acc1 = 0.f;

    auto step = [&](float xv, float2 ea, bool valid, float& mx, float& den, float& acc) {
        float tv = lrelu(xv + xrv + ea.x * we0 + ea.y * we1, 0.2f) * av;
        tv += __shfl_xor(tv, 1);
        tv += __shfl_xor(tv, 2);
        if (!valid) tv = -__builtin_inff();
        float nm = fmaxf(mx, tv);
        float sc = __expf(mx - nm), w = __expf(tv - nm);
        den = den * sc + w;
        acc = acc * sc + w * xv;
        mx = nm;
    };

    for (int p = p0; p < p1; p += 4) {
        int q1 = min(p + 1, p1 - 1), q2 = min(p + 2, p1 - 1), q3 = min(p + 3, p1 - 1);
        int s0 = csr_src[p], s1 = csr_src[q1], s2 = csr_src[q2], s3 = csr_src[q3];
        float2 e0 = *(const float2*)(csr_ea + 2 * (size_t)p);
        float2 e1 = *(const float2*)(csr_ea + 2 * (size_t)q1);
        float2 e2 = *(const float2*)(csr_ea + 2 * (size_t)q2);
        float2 e3 = *(const float2*)(csr_ea + 2 * (size_t)q3);
        float x0 = xl[(size_t)s0 * 64 + lane];
        float x1 = xl[(size_t)s1 * 64 + lane];
        float x2 = xl[(size_t)s2 * 64 + lane];
        float x3 = xl[(size_t)s3 * 64 + lane];
        step(x0, e0, true, mx0, den0, acc0);
        step(x1, e1, p + 1 < p1, mx1, den1, acc1);
        step(x2, e2, p + 2 < p1, mx0, den0, acc0);
        step(x3, e3, p + 3 < p1, mx1, den1, acc1);
    }
    // merge the two accumulator chains (chain1 may be empty: mx1=-3e38 -> sc1=0)
    float nm = fmaxf(mx0, mx1);
    float sc0 = __expf(mx0 - nm), sc1 = __expf(mx1 - nm);
    float den = den0 * sc0 + den1 * sc1;
    float acc = acc0 * sc0 + acc1 * sc1;

    float o = acc / den + bias[lane];
    if (relu) o = lrelu(o, 0.01f);
    out[(size_t)d * 64 + lane] = o;
}

// ---------------- final two H=16,C=1 layers fused ----------------
// half-wave per dst: lanes 0-15 = f (-> fin), 16-31 = s (-> mus). Online softmax.
__launch_bounds__(256)
__global__ void k_gat_final(const float* __restrict__ packed,
                            const int* __restrict__ row_ptr, const int* __restrict__ csr_src,
                            const float* __restrict__ csr_ea,
                            const float* __restrict__ fWe, const float* __restrict__ sWe,
                            const float* __restrict__ fatt, const float* __restrict__ satt,
                            const float* __restrict__ fbias, const float* __restrict__ sbias,
                            float* __restrict__ fin, float* __restrict__ mus, int n) {
    int hw = (blockIdx.x * blockDim.x + threadIdx.x) >> 5;
    if (hw >= n) return;
    int l = threadIdx.x & 31;
    int hh = l & 15, sel = l >> 4;
    const int d = hw;
    const int p0 = row_ptr[d], p1 = row_ptr[d + 1];
    const float* We = sel ? sWe : fWe;
    float we0 = We[hh], we1 = We[16 + hh];
    float av = (sel ? satt : fatt)[hh];
    float xrv = packed[(size_t)d * 64 + 32 + sel * 16 + hh];
    int xli = sel * 16 + hh;

    float mx0 = -3.0e38f, den0 = 0.f, acc0 = 0.f;
    float mx1 = -3.0e38f, den1 = 0.f, acc1 = 0.f;

    auto step = [&](float xv, float2 ea, bool valid, float& mx, float& den, float& acc) {
        float t = lrelu(xv + xrv + ea.x * we0 + ea.y * we1, 0.2f) * av;
        if (!valid) t = -__builtin_inff();
        float nm = fmaxf(mx, t);
        float sc = __expf(mx - nm), w = __expf(t - nm);
        den = den * sc + w;
        acc = acc * sc + w * xv;
        mx = nm;
    };

    for (int p = p0; p < p1; p += 4) {
        int q1 = min(p + 1, p1 - 1), q2 = min(p + 2, p1 - 1), q3 = min(p + 3, p1 - 1);
        int s0 = csr_src[p], s1 = csr_src[q1], s2 = csr_src[q2], s3 = csr_src[q3];
        float2 e0 = *(const float2*)(csr_ea + 2 * (size_t)p);
        float2 e1 = *(const float2*)(csr_ea + 2 * (size_t)q1);
        float2 e2 = *(const float2*)(csr_ea + 2 * (size_t)q2);
        float2 e3 = *(const float2*)(csr_ea + 2 * (size_t)q3);
        float x0 = packed[(size_t)s0 * 64 + xli];
        float x1 = packed[(size_t)s1 * 64 + xli];
        float x2 = packed[(size_t)s2 * 64 + xli];
        float x3 = packed[(size_t)s3 * 64 + xli];
        step(x0, e0, true, mx0, den0, acc0);
        step(x1, e1, p + 1 < p1, mx1, den1, acc1);
        step(x2, e2, p + 2 < p1, mx0, den0, acc0);
        step(x3, e3, p + 3 < p1, mx1, den1, acc1);
    }
    float nm = fmaxf(mx0, mx1);
    float sc0 = __expf(mx0 - nm), sc1 = __expf(mx1 - nm);
    float val = (acc0 * sc0 + acc1 * sc1) / (den0 * sc0 + den1 * sc1);
#pragma unroll
    for (int w = 1; w < 16; w <<= 1) val += __shfl_xor(val, w);
    if ((threadIdx.x & 15) == 0) {
        float o = val * (1.f / 16.f) + (sel ? sbias[0] : fbias[0]);
        if (sel) mus[d] = o; else fin[d] = o;
    }
}

// ---------------- batchnorm ----------------

__global__ void k_bnstats(const float* __restrict__ h, double* __restrict__ stats, int n) {
    int c = threadIdx.x & 63;
    int s0 = blockIdx.x * (blockDim.x >> 6) + (threadIdx.x >> 6);
    int ns = gridDim.x * (blockDim.x >> 6);
    double s = 0.0, s2 = 0.0;
    for (int i = s0; i < n; i += ns) {
        float v = h[(size_t)i * 64 + c];
        s += v;
        s2 += (double)v * v;
    }
    atomicAdd(&stats[c], s);
    atomicAdd(&stats[64 + c], s2);
}

__global__ void k_bnapply(float* __restrict__ h, const double* __restrict__ stats,
                          const float* __restrict__ gamma, const float* __restrict__ beta, int n) {
    int idx = blockIdx.x * blockDim.x + threadIdx.x;
    if (idx >= n * 64) return;
    int c = idx & 63;
    double mu = stats[c] / n;
    double var = stats[64 + c] / n - mu * mu;
    float rs = (float)(1.0 / sqrt(var + 1e-5));
    float v = (h[idx] - (float)mu) * rs * gamma[c] + beta[c];
    h[idx] = lrelu(v, 0.01f);
}

// ---------------- graph-level mean over masked nodes ----------------
// batch is sorted -> wave-level segmented reduction, one atomic per run head.
__global__ void k_sat_acc(const float* __restrict__ fin, const int* __restrict__ mask,
                          const int* __restrict__ batch,
                          float* __restrict__ sums, float* __restrict__ cnts, int n) {
    int i = blockIdx.x * blockDim.x + threadIdx.x;
    int lane = threadIdx.x & 63;
    int g = (i < n) ? batch[i] : -1;
    float c = (i < n && mask[i] == 0) ? 1.f : 0.f;
    float v = (c > 0.f) ? fin[i] : 0.f;
#pragma unroll
    for (int off = 1; off < 64; off <<= 1) {
        float v2 = __shfl_down(v, off);
        float c2 = __shfl_down(c, off);
        int g2 = __shfl_down(g, off);
        if (lane + off < 64 && g2 == g) { v += v2; c += c2; }
    }
    int gprev = __shfl_up(g, 1);
    bool head = (lane == 0) || (gprev != g);
    if (head && g >= 0 && c > 0.f) {
        atomicAdd(&sums[g], v);
        atomicAdd(&cnts[g], c);
    }
}

__global__ void k_sat_fin(const float* __restrict__ sums, const float* __restrict__ cnts,
                          float* __restrict__ out, int g) {
    int i = threadIdx.x;
    if (i < g) out[i] = sums[i] / fmaxf(cnts[i], 1.f);
}

// ---------------- host ----------------

extern "C" void kernel_launch(void* const* d_in, const int* in_sizes, int n_in,
                              void* d_out, int out_size, void* d_ws, size_t ws_size,
                              hipStream_t stream) {
    const float* x = (const float*)d_in[0];
    const float* eat = (const float*)d_in[1];
    const int* ei = (const int*)d_in[2];
    const int* mask = (const int*)d_in[3];
    const int* batch = (const int*)d_in[4];
    const float* g0_Wl = (const float*)d_in[5];
    const float* g0_bl = (const float*)d_in[6];
    const float* g0_Wr = (const float*)d_in[7];
    const float* g0_br = (const float*)d_in[8];
    const float* g0_We = (const float*)d_in[9];
    const float* g0_att = (const float*)d_in[10];
    const float* g0_bias = (const float*)d_in[11];
    const float* bn_g = (const float*)d_in[12];
    const float* bn_b = (const float*)d_in[13];
    const float* m_Wl = (const float*)d_in[14];
    const float* m_bl = (const float*)d_in[15];
    const float* m_Wr = (const float*)d_in[16];
    const float* m_br = (const float*)d_in[17];
    const float* m_We = (const float*)d_in[18];
    const float* m_att = (const float*)d_in[19];
    const float* m_bias = (const float*)d_in[20];
    const float* f_Wl = (const float*)d_in[21];
    const float* f_bl = (const float*)d_in[22];
    const float* f_Wr = (const float*)d_in[23];
    const float* f_br = (const float*)d_in[24];
    const float* f_We = (const float*)d_in[25];
    const float* f_att = (const float*)d_in[26];
    const float* f_bias = (const float*)d_in[27];
    const float* s_Wl = (const float*)d_in[28];
    const float* s_bl = (const float*)d_in[29];
    const float* s_Wr = (const float*)d_in[30];
    const float* s_br = (const float*)d_in[31];
    const float* s_We = (const float*)d_in[32];
    const float* s_att = (const float*)d_in[33];
    const float* s_bias = (const float*)d_in[34];

    const int N = in_sizes[3];
    const int E = in_sizes[1] / 2;
    const int G = out_size - N;
    const int ITER = in_sizes[14] / 4096;
    const int ET = E + N;
    const int* srcp = ei;
    const int* dstp = ei + E;

    char* wsb = (char*)d_ws;
    size_t off = 0;
    auto alloc = [&](size_t b) { void* p = wsb + off; off = (off + b + 255) & ~(size_t)255; return p; };
    int* cnt = (int*)alloc((size_t)N * 4);
    double* stats = (double*)alloc(128 * 8);
    float* sums = (float*)alloc((size_t)G * 4);
    float* cnts = (float*)alloc((size_t)G * 4);
    size_t zero_bytes = off;
    int* rank = (int*)alloc((size_t)E * 4);
    int* row_ptr = (int*)alloc((size_t)(N + 1) * 4);
    int* csr_src = (int*)alloc((size_t)ET * 4);
    float* csr_ea = (float*)alloc((size_t)ET * 8);
    float* xl = (float*)alloc((size_t)N * 256);
    float* xr = (float*)alloc((size_t)N * 256);
    float* hbuf = (float*)alloc((size_t)N * 256);
    float* fin = (float*)alloc((size_t)N * 4);
    (void)ws_size; (void)n_in;

    float* outv = (float*)d_out;  // [0,N) = mus, [N,N+G) = sat

    hipMemsetAsync(d_ws, 0, zero_bytes, stream);
    const int tb = 256;
    k_degree<<<(E + tb - 1) / tb, tb, 0, stream>>>(dstp, cnt, rank, E);
    k_rowptr<<<1, 1024, 0, stream>>>(cnt, row_ptr, N);
    k_scatter<<<(E + tb - 1) / tb, tb, 0, stream>>>(srcp, dstp, eat, rank, row_ptr, csr_src, csr_ea, E);
    k_selfloop<<<(N + tb - 1) / tb, tb, 0, stream>>>(row_ptr, csr_src, csr_ea, N);

    k_proj0<<<(N * 64 + tb - 1) / tb, tb, 0, stream>>>(x, g0_Wl, g0_bl, g0_Wr, g0_br, xl, xr, N);
    k_gat<<<(N * 64 + tb - 1) / tb, tb, 0, stream>>>(xl, xr, row_ptr, csr_src, csr_ea,
                                                     g0_We, g0_att, g0_bias, hbuf, N, 0);
    k_bnstats<<<128, 256, 0, stream>>>(hbuf, stats, N);
    k_bnapply<<<(N * 64 + tb - 1) / tb, tb, 0, stream>>>(hbuf, stats, bn_g, bn_b, N);

    dim3 gp((N + 255) / 256, 2);
    for (int l = 0; l < ITER; ++l) {
        k_proj64_dual<<<gp, 256, 0, stream>>>(hbuf, m_Wl + (size_t)l * 4096, m_bl + l * 64,
                                              m_Wr + (size_t)l * 4096, m_br + l * 64, xl, xr, N);
        k_gat<<<(N * 64 + tb - 1) / tb, tb, 0, stream>>>(xl, xr, row_ptr, csr_src, csr_ea,
                                                         m_We + l * 128, m_att + l * 64,
                                                         m_bias + l * 64, hbuf, N, 1);
    }
    k_proj_final<<<(N + 255) / 256, 256, 0, stream>>>(hbuf, f_Wl, f_bl, f_Wr, f_br,
                                                      s_Wl, s_bl, s_Wr, s_br, xl, N);
    k_gat_final<<<(N * 32 + tb - 1) / tb, tb, 0, stream>>>(xl, row_ptr, csr_src, csr_ea,
                                                           f_We, s_We, f_att, s_att,
                                                           f_bias, s_bias, fin, outv, N);
    k_sat_acc<<<(N + tb - 1) / tb, tb, 0, stream>>>(fin, mask, batch, sums, cnts, N);
    k_sat_fin<<<1, 64, 0, stream>>>(sums, cnts, outv + N, G);
}

// Round 5
// 832.043 us; speedup vs baseline: 2.0549x; 1.0010x over previous
//
#include <hip/hip_runtime.h>

// GATv2 stack on MI355X. fp32 throughout (no fp32 MFMA on CDNA4 -> vector ALU).
// R4: k_gat unroll-8 with 4 independent online-softmax chains (8 gathers in
// flight -> latency hiding); projection computes Wl and Wr in one pass (h read
// once per layer instead of twice).

static __device__ __forceinline__ float lrelu(float x, float s) {
    return x > 0.f ? x : s * x;
}

// ---------------- graph build ----------------

__global__ void k_degree(const int* __restrict__ dst, int* __restrict__ cnt,
                         int* __restrict__ rank, int E) {
    int e = blockIdx.x * blockDim.x + threadIdx.x;
    if (e >= E) return;
    rank[e] = atomicAdd(&cnt[dst[e]], 1);
}

__launch_bounds__(1024)
__global__ void k_rowptr(const int* __restrict__ cnt, int* __restrict__ row_ptr, int n) {
    __shared__ int tot[1024];
    int t = threadIdx.x;
    int chunk = (n + 1023) >> 10;
    int b = min(t * chunk, n), e = min(b + chunk, n);
    int s = 0;
    for (int i = b; i < e; ++i) s += cnt[i] + 1;
    tot[t] = s;
    __syncthreads();
    for (int off = 1; off < 1024; off <<= 1) {
        int v = (t >= off) ? tot[t - off] : 0;
        __syncthreads();
        tot[t] += v;
        __syncthreads();
    }
    int run = (t > 0) ? tot[t - 1] : 0;
    for (int i = b; i < e; ++i) { row_ptr[i] = run; run += cnt[i] + 1; }
    if (t == 1023) row_ptr[n] = run;
}

__global__ void k_scatter(const int* __restrict__ src, const int* __restrict__ dst,
                          const float* __restrict__ ea, const int* __restrict__ rank,
                          const int* __restrict__ row_ptr,
                          int* __restrict__ csr_src, float* __restrict__ csr_ea, int E) {
    int e = blockIdx.x * blockDim.x + threadIdx.x;
    if (e >= E) return;
    int pos = row_ptr[dst[e]] + rank[e];
    csr_src[pos] = src[e];
    csr_ea[2 * (size_t)pos] = ea[2 * (size_t)e];
    csr_ea[2 * (size_t)pos + 1] = ea[2 * (size_t)e + 1];
}

__global__ void k_selfloop(const int* __restrict__ row_ptr,
                           int* __restrict__ csr_src, float* __restrict__ csr_ea, int n) {
    int i = blockIdx.x * blockDim.x + threadIdx.x;
    if (i >= n) return;
    int p0 = row_ptr[i], p1 = row_ptr[i + 1];
    float s0 = 0.f, s1 = 0.f;
    for (int p = p0; p < p1 - 1; ++p) {
        s0 += csr_ea[2 * (size_t)p];
        s1 += csr_ea[2 * (size_t)p + 1];
    }
    float c = fmaxf((float)(p1 - 1 - p0), 1.f);
    csr_src[p1 - 1] = i;
    csr_ea[2 * (size_t)(p1 - 1)] = s0 / c;
    csr_ea[2 * (size_t)(p1 - 1) + 1] = s1 / c;
}

// ---------------- projections ----------------

__global__ void k_proj0(const float* __restrict__ x,
                        const float* __restrict__ Wl, const float* __restrict__ bl,
                        const float* __restrict__ Wr, const float* __restrict__ br,
                        float* __restrict__ xl, float* __restrict__ xr, int n) {
    int idx = blockIdx.x * blockDim.x + threadIdx.x;
    if (idx >= n * 64) return;
    int i = idx >> 6, c = idx & 63;
    float x0 = x[2 * i], x1 = x[2 * i + 1];
    xl[idx] = x0 * Wl[c] + x1 * Wl[64 + c] + bl[c];
    xr[idx] = x0 * Wr[c] + x1 * Wr[64 + c] + br[c];
}

// h[N,64] @ {Wl,Wr}[64,64] + {bl,br} in ONE pass (h read once).
// thread: 2 rows x 16 cols x 2 matrices. block covers 128 rows.
__launch_bounds__(256)
__global__ void k_proj64(const float* __restrict__ h,
                         const float* __restrict__ Wl, const float* __restrict__ bl,
                         const float* __restrict__ Wr, const float* __restrict__ br,
                         float* __restrict__ xl, float* __restrict__ xr, int n) {
    __shared__ float wsl[4096], wsr[4096];
    int t = threadIdx.x;
    for (int i = t; i < 4096; i += 256) { wsl[i] = Wl[i]; wsr[i] = Wr[i]; }
    __syncthreads();
    int rg = t >> 2, cg = (t & 3) << 4;
    int r0 = blockIdx.x * 128 + rg * 2;
    float accl[2][16], accr[2][16];
#pragma unroll
    for (int r = 0; r < 2; ++r)
#pragma unroll
        for (int j = 0; j < 16; ++j) { accl[r][j] = 0.f; accr[r][j] = 0.f; }
    for (int k0 = 0; k0 < 64; k0 += 4) {
        float hk[2][4];
#pragma unroll
        for (int r = 0; r < 2; ++r) {
            int gr = r0 + r;
            float4 v = (gr < n) ? *(const float4*)(h + (size_t)gr * 64 + k0)
                                : make_float4(0.f, 0.f, 0.f, 0.f);
            hk[r][0] = v.x; hk[r][1] = v.y; hk[r][2] = v.z; hk[r][3] = v.w;
        }
#pragma unroll
        for (int kk = 0; kk < 4; ++kk) {
            const float* wl = wsl + (k0 + kk) * 64 + cg;
            const float* wr = wsr + (k0 + kk) * 64 + cg;
#pragma unroll
            for (int r = 0; r < 2; ++r)
#pragma unroll
                for (int j = 0; j < 16; ++j) {
                    accl[r][j] += hk[r][kk] * wl[j];
                    accr[r][j] += hk[r][kk] * wr[j];
                }
        }
    }
#pragma unroll
    for (int r = 0; r < 2; ++r) {
        int gr = r0 + r;
        if (gr < n) {
            float* ol = xl + (size_t)gr * 64 + cg;
            float* orr = xr + (size_t)gr * 64 + cg;
#pragma unroll
            for (int j = 0; j < 16; ++j) {
                ol[j] = accl[r][j] + bl[cg + j];
                orr[j] = accr[r][j] + br[cg + j];
            }
        }
    }
}

// final projections fused: packed[i][0:16)=f_xl, [16:32)=s_xl, [32:48)=f_xr, [48:64)=s_xr
__launch_bounds__(256)
__global__ void k_proj_final(const float* __restrict__ h,
                             const float* __restrict__ fWl, const float* __restrict__ fbl,
                             const float* __restrict__ fWr, const float* __restrict__ fbr,
                             const float* __restrict__ sWl, const float* __restrict__ sbl,
                             const float* __restrict__ sWr, const float* __restrict__ sbr,
                             float* __restrict__ packed, int n) {
    __shared__ float ws[4096];
    __shared__ float bs[64];
    int t = threadIdx.x;
    for (int i = t; i < 1024; i += 256) {
        int k = i >> 4, j = i & 15;
        ws[k * 64 + j] = fWl[i];
        ws[k * 64 + 16 + j] = sWl[i];
        ws[k * 64 + 32 + j] = fWr[i];
        ws[k * 64 + 48 + j] = sWr[i];
    }
    if (t < 16) { bs[t] = fbl[t]; bs[16 + t] = sbl[t]; bs[32 + t] = fbr[t]; bs[48 + t] = sbr[t]; }
    __syncthreads();
    int rg = t >> 2, cg = (t & 3) << 4;
    int r0 = blockIdx.x * 256 + rg * 4;
    float acc[4][16];
#pragma unroll
    for (int r = 0; r < 4; ++r)
#pragma unroll
        for (int j = 0; j < 16; ++j) acc[r][j] = 0.f;
    for (int k0 = 0; k0 < 64; k0 += 4) {
        float hk[4][4];
#pragma unroll
        for (int r = 0; r < 4; ++r) {
            int gr = r0 + r;
            float4 v = (gr < n) ? *(const float4*)(h + (size_t)gr * 64 + k0)
                                : make_float4(0.f, 0.f, 0.f, 0.f);
            hk[r][0] = v.x; hk[r][1] = v.y; hk[r][2] = v.z; hk[r][3] = v.w;
        }
#pragma unroll
        for (int kk = 0; kk < 4; ++kk) {
            const float* wrow = ws + (k0 + kk) * 64 + cg;
#pragma unroll
            for (int r = 0; r < 4; ++r)
#pragma unroll
                for (int j = 0; j < 16; ++j) acc[r][j] += hk[r][kk] * wrow[j];
        }
    }
#pragma unroll
    for (int r = 0; r < 4; ++r) {
        int gr = r0 + r;
        if (gr < n) {
            float* o = packed + (size_t)gr * 64 + cg;
#pragma unroll
            for (int j = 0; j < 16; ++j) o[j] = acc[r][j] + bs[cg + j];
        }
    }
}

// ---------------- GATv2 attention, 64-feature layers ----------------
// one wave per dst node; lane = head*4 + channel. Online softmax, unroll-8,
// 4 independent accumulator chains (8 gathers in flight).
__launch_bounds__(256)
__global__ void k_gat(const float* __restrict__ xl, const float* __restrict__ xr,
                      const int* __restrict__ row_ptr, const int* __restrict__ csr_src,
                      const float* __restrict__ csr_ea,
                      const float* __restrict__ We,   // [2,64]
                      const float* __restrict__ att,  // [16,4] flat
                      const float* __restrict__ bias, // [64]
                      float* __restrict__ out, int n, int relu) {
    int wave = (blockIdx.x * blockDim.x + threadIdx.x) >> 6;
    int lane = threadIdx.x & 63;
    if (wave >= n) return;
    const int d = wave;
    const int p0 = __builtin_amdgcn_readfirstlane(row_ptr[d]);
    const int p1 = __builtin_amdgcn_readfirstlane(row_ptr[d + 1]);
    const float we0 = We[lane], we1 = We[64 + lane];
    const float av = att[lane];
    const float xrv = xr[(size_t)d * 64 + lane];

    float mx[4] = {-3.0e38f, -3.0e38f, -3.0e38f, -3.0e38f};
    float den[4] = {0.f, 0.f, 0.f, 0.f};
    float acc[4] = {0.f, 0.f, 0.f, 0.f};

    auto step = [&](float xv, float2 ea, bool valid, int c) {
        float tv = lrelu(xv + xrv + ea.x * we0 + ea.y * we1, 0.2f) * av;
        tv += __shfl_xor(tv, 1);
        tv += __shfl_xor(tv, 2);
        if (!valid) tv = -__builtin_inff();
        float nm = fmaxf(mx[c], tv);
        float sc = __expf(mx[c] - nm), w = __expf(tv - nm);
        den[c] = den[c] * sc + w;
        acc[c] = acc[c] * sc + w * xv;
        mx[c] = nm;
    };

    for (int p = p0; p < p1; p += 8) {
        int q[8], s[8];
        float2 ev[8];
        float xv[8];
#pragma unroll
        for (int u = 0; u < 8; ++u) q[u] = min(p + u, p1 - 1);
#pragma unroll
        for (int u = 0; u < 8; ++u) s[u] = csr_src[q[u]];
#pragma unroll
        for (int u = 0; u < 8; ++u) ev[u] = *(const float2*)(csr_ea + 2 * (size_t)q[u]);
#pragma unroll
        for (int u = 0; u < 8; ++u) xv[u] = xl[(size_t)s[u] * 64 + lane];
#pragma unroll
        for (int u = 0; u < 8; ++u) step(xv[u], ev[u], p + u < p1, u & 3);
    }
    // merge 4 chains (empty chains have mx=-3e38 -> weight 0)
    float nm = fmaxf(fmaxf(mx[0], mx[1]), fmaxf(mx[2], mx[3]));
    float D = 0.f, A = 0.f;
#pragma unroll
    for (int c = 0; c < 4; ++c) {
        float sc = __expf(mx[c] - nm);
        D += den[c] * sc;
        A += acc[c] * sc;
    }
    float o = A / D + bias[lane];
    if (relu) o = lrelu(o, 0.01f);
    out[(size_t)d * 64 + lane] = o;
}

// ---------------- final two H=16,C=1 layers fused ----------------
// half-wave per dst: lanes 0-15 = f (-> fin), 16-31 = s (-> mus).
__launch_bounds__(256)
__global__ void k_gat_final(const float* __restrict__ packed,
                            const int* __restrict__ row_ptr, const int* __restrict__ csr_src,
                            const float* __restrict__ csr_ea,
                            const float* __restrict__ fWe, const float* __restrict__ sWe,
                            const float* __restrict__ fatt, const float* __restrict__ satt,
                            const float* __restrict__ fbias, const float* __restrict__ sbias,
                            float* __restrict__ fin, float* __restrict__ mus, int n) {
    int hw = (blockIdx.x * blockDim.x + threadIdx.x) >> 5;
    if (hw >= n) return;
    int l = threadIdx.x & 31;
    int hh = l & 15, sel = l >> 4;
    const int d = hw;
    const int p0 = row_ptr[d], p1 = row_ptr[d + 1];
    const float* We = sel ? sWe : fWe;
    float we0 = We[hh], we1 = We[16 + hh];
    float av = (sel ? satt : fatt)[hh];
    float xrv = packed[(size_t)d * 64 + 32 + sel * 16 + hh];
    int xli = sel * 16 + hh;

    float mx[4] = {-3.0e38f, -3.0e38f, -3.0e38f, -3.0e38f};
    float den[4] = {0.f, 0.f, 0.f, 0.f};
    float acc[4] = {0.f, 0.f, 0.f, 0.f};

    auto step = [&](float xv, float2 ea, bool valid, int c) {
        float t = lrelu(xv + xrv + ea.x * we0 + ea.y * we1, 0.2f) * av;
        if (!valid) t = -__builtin_inff();
        float nm = fmaxf(mx[c], t);
        float sc = __expf(mx[c] - nm), w = __expf(t - nm);
        den[c] = den[c] * sc + w;
        acc[c] = acc[c] * sc + w * xv;
        mx[c] = nm;
    };

    for (int p = p0; p < p1; p += 8) {
        int q[8], s[8];
        float2 ev[8];
        float xv[8];
#pragma unroll
        for (int u = 0; u < 8; ++u) q[u] = min(p + u, p1 - 1);
#pragma unroll
        for (int u = 0; u < 8; ++u) s[u] = csr_src[q[u]];
#pragma unroll
        for (int u = 0; u < 8; ++u) ev[u] = *(const float2*)(csr_ea + 2 * (size_t)q[u]);
#pragma unroll
        for (int u = 0; u < 8; ++u) xv[u] = packed[(size_t)s[u] * 64 + xli];
#pragma unroll
        for (int u = 0; u < 8; ++u) step(xv[u], ev[u], p + u < p1, u & 3);
    }
    float nm = fmaxf(fmaxf(mx[0], mx[1]), fmaxf(mx[2], mx[3]));
    float D = 0.f, A = 0.f;
#pragma unroll
    for (int c = 0; c < 4; ++c) {
        float sc = __expf(mx[c] - nm);
        D += den[c] * sc;
        A += acc[c] * sc;
    }
    float val = A / D;
#pragma unroll
    for (int w = 1; w < 16; w <<= 1) val += __shfl_xor(val, w);
    if ((threadIdx.x & 15) == 0) {
        float o = val * (1.f / 16.f) + (sel ? sbias[0] : fbias[0]);
        if (sel) mus[d] = o; else fin[d] = o;
    }
}

// ---------------- batchnorm ----------------

__global__ void k_bnstats(const float* __restrict__ h, double* __restrict__ stats, int n) {
    int c = threadIdx.x & 63;
    int s0 = blockIdx.x * (blockDim.x >> 6) + (threadIdx.x >> 6);
    int ns = gridDim.x * (blockDim.x >> 6);
    double s = 0.0, s2 = 0.0;
    for (int i = s0; i < n; i += ns) {
        float v = h[(size_t)i * 64 + c];
        s += v;
        s2 += (double)v * v;
    }
    atomicAdd(&stats[c], s);
    atomicAdd(&stats[64 + c], s2);
}

__global__ void k_bnapply(float* __restrict__ h, const double* __restrict__ stats,
                          const float* __restrict__ gamma, const float* __restrict__ beta, int n) {
    int idx = blockIdx.x * blockDim.x + threadIdx.x;
    if (idx >= n * 64) return;
    int c = idx & 63;
    double mu = stats[c] / n;
    double var = stats[64 + c] / n - mu * mu;
    float rs = (float)(1.0 / sqrt(var + 1e-5));
    float v = (h[idx] - (float)mu) * rs * gamma[c] + beta[c];
    h[idx] = lrelu(v, 0.01f);
}

// ---------------- graph-level mean over masked nodes ----------------

__global__ void k_sat_acc(const float* __restrict__ fin, const int* __restrict__ mask,
                          const int* __restrict__ batch,
                          float* __restrict__ sums, float* __restrict__ cnts, int n) {
    int i = blockIdx.x * blockDim.x + threadIdx.x;
    int lane = threadIdx.x & 63;
    int g = (i < n) ? batch[i] : -1;
    float c = (i < n && mask[i] == 0) ? 1.f : 0.f;
    float v = (c > 0.f) ? fin[i] : 0.f;
#pragma unroll
    for (int off = 1; off < 64; off <<= 1) {
        float v2 = __shfl_down(v, off);
        float c2 = __shfl_down(c, off);
        int g2 = __shfl_down(g, off);
        if (lane + off < 64 && g2 == g) { v += v2; c += c2; }
    }
    int gprev = __shfl_up(g, 1);
    bool head = (lane == 0) || (gprev != g);
    if (head && g >= 0 && c > 0.f) {
        atomicAdd(&sums[g], v);
        atomicAdd(&cnts[g], c);
    }
}

__global__ void k_sat_fin(const float* __restrict__ sums, const float* __restrict__ cnts,
                          float* __restrict__ out, int g) {
    int i = threadIdx.x;
    if (i < g) out[i] = sums[i] / fmaxf(cnts[i], 1.f);
}

// ---------------- host ----------------

extern "C" void kernel_launch(void* const* d_in, const int* in_sizes, int n_in,
                              void* d_out, int out_size, void* d_ws, size_t ws_size,
                              hipStream_t stream) {
    const float* x = (const float*)d_in[0];
    const float* eat = (const float*)d_in[1];
    const int* ei = (const int*)d_in[2];
    const int* mask = (const int*)d_in[3];
    const int* batch = (const int*)d_in[4];
    const float* g0_Wl = (const float*)d_in[5];
    const float* g0_bl = (const float*)d_in[6];
    const float* g0_Wr = (const float*)d_in[7];
    const float* g0_br = (const float*)d_in[8];
    const float* g0_We = (const float*)d_in[9];
    const float* g0_att = (const float*)d_in[10];
    const float* g0_bias = (const float*)d_in[11];
    const float* bn_g = (const float*)d_in[12];
    const float* bn_b = (const float*)d_in[13];
    const float* m_Wl = (const float*)d_in[14];
    const float* m_bl = (const float*)d_in[15];
    const float* m_Wr = (const float*)d_in[16];
    const float* m_br = (const float*)d_in[17];
    const float* m_We = (const float*)d_in[18];
    const float* m_att = (const float*)d_in[19];
    const float* m_bias = (const float*)d_in[20];
    const float* f_Wl = (const float*)d_in[21];
    const float* f_bl = (const float*)d_in[22];
    const float* f_Wr = (const float*)d_in[23];
    const float* f_br = (const float*)d_in[24];
    const float* f_We = (const float*)d_in[25];
    const float* f_att = (const float*)d_in[26];
    const float* f_bias = (const float*)d_in[27];
    const float* s_Wl = (const float*)d_in[28];
    const float* s_bl = (const float*)d_in[29];
    const float* s_Wr = (const float*)d_in[30];
    const float* s_br = (const float*)d_in[31];
    const float* s_We = (const float*)d_in[32];
    const float* s_att = (const float*)d_in[33];
    const float* s_bias = (const float*)d_in[34];

    const int N = in_sizes[3];
    const int E = in_sizes[1] / 2;
    const int G = out_size - N;
    const int ITER = in_sizes[14] / 4096;
    const int ET = E + N;
    const int* srcp = ei;
    const int* dstp = ei + E;

    char* wsb = (char*)d_ws;
    size_t off = 0;
    auto alloc = [&](size_t b) { void* p = wsb + off; off = (off + b + 255) & ~(size_t)255; return p; };
    int* cnt = (int*)alloc((size_t)N * 4);
    double* stats = (double*)alloc(128 * 8);
    float* sums = (float*)alloc((size_t)G * 4);
    float* cnts = (float*)alloc((size_t)G * 4);
    size_t zero_bytes = off;
    int* rank = (int*)alloc((size_t)E * 4);
    int* row_ptr = (int*)alloc((size_t)(N + 1) * 4);
    int* csr_src = (int*)alloc((size_t)ET * 4);
    float* csr_ea = (float*)alloc((size_t)ET * 8);
    float* xl = (float*)alloc((size_t)N * 256);
    float* xr = (float*)alloc((size_t)N * 256);
    float* hbuf = (float*)alloc((size_t)N * 256);
    float* fin = (float*)alloc((size_t)N * 4);
    (void)ws_size; (void)n_in;

    float* outv = (float*)d_out;  // [0,N) = mus, [N,N+G) = sat

    hipMemsetAsync(d_ws, 0, zero_bytes, stream);
    const int tb = 256;
    k_degree<<<(E + tb - 1) / tb, tb, 0, stream>>>(dstp, cnt, rank, E);
    k_rowptr<<<1, 1024, 0, stream>>>(cnt, row_ptr, N);
    k_scatter<<<(E + tb - 1) / tb, tb, 0, stream>>>(srcp, dstp, eat, rank, row_ptr, csr_src, csr_ea, E);
    k_selfloop<<<(N + tb - 1) / tb, tb, 0, stream>>>(row_ptr, csr_src, csr_ea, N);

    k_proj0<<<(N * 64 + tb - 1) / tb, tb, 0, stream>>>(x, g0_Wl, g0_bl, g0_Wr, g0_br, xl, xr, N);
    k_gat<<<(N * 64 + tb - 1) / tb, tb, 0, stream>>>(xl, xr, row_ptr, csr_src, csr_ea,
                                                     g0_We, g0_att, g0_bias, hbuf, N, 0);
    k_bnstats<<<128, 256, 0, stream>>>(hbuf, stats, N);
    k_bnapply<<<(N * 64 + tb - 1) / tb, tb, 0, stream>>>(hbuf, stats, bn_g, bn_b, N);

    int gp = (N + 127) / 128;
    for (int l = 0; l < ITER; ++l) {
        k_proj64<<<gp, 256, 0, stream>>>(hbuf, m_Wl + (size_t)l * 4096, m_bl + l * 64,
                                         m_Wr + (size_t)l * 4096, m_br + l * 64, xl, xr, N);
        k_gat<<<(N * 64 + tb - 1) / tb, tb, 0, stream>>>(xl, xr, row_ptr, csr_src, csr_ea,
                                                         m_We + l * 128, m_att + l * 64,
                                                         m_bias + l * 64, hbuf, N, 1);
    }
    k_proj_final<<<(N + 255) / 256, 256, 0, stream>>>(hbuf, f_Wl, f_bl, f_Wr, f_br,
                                                      s_Wl, s_bl, s_Wr, s_br, xl, N);
    k_gat_final<<<(N * 32 + tb - 1) / tb, tb, 0, stream>>>(xl, row_ptr, csr_src, csr_ea,
                                                           f_We, s_We, f_att, s_att,
                                                           f_bias, s_bias, fin, outv, N);
    k_sat_acc<<<(N + tb - 1) / tb, tb, 0, stream>>>(fin, mask, batch, sums, cnts, N);
    k_sat_fin<<<1, 64, 0, stream>>>(sums, cnts, outv + N, G);
}